// Round 7
// baseline (787.976 us; speedup 1.0000x reference)
//
#include <hip/hip_runtime.h>

typedef unsigned short u16;
typedef __bf16 bf16x8 __attribute__((ext_vector_type(8)));
typedef float f32x4 __attribute__((ext_vector_type(4)));

typedef const __attribute__((address_space(1))) void gv_t;
typedef __attribute__((address_space(3))) void lv_t;

__device__ __forceinline__ float b2f(u16 u) {
    union { unsigned int i; float f; } v; v.i = ((unsigned int)u) << 16; return v.f;
}
__device__ __forceinline__ u16 f2b(float f) {
    union { unsigned int i; float f; } v; v.f = f;
    unsigned int b = v.i;
    return (u16)((b + 0x7FFFu + ((b >> 16) & 1u)) >> 16);
}

// Hamilton product tables: out component p, input component q -> weight index / sign
__constant__ int   c_qidx[16] = {0,1,2,3, 1,0,3,2, 2,3,0,1, 3,2,1,0};
__constant__ float c_qsgn[16] = {1,-1,-1,-1, 1,1,1,-1, 1,-1,1,1, 1,1,-1,1};

// ---------------------------------------------------------------- weights ---
// GEMM weights stored in MFMA-fragment order:
//   u16 idx = ((((mtile*KT + ktile)*8 + frag)*4 + quad)*16 + r16)*8 + j
// so a wave's A-fragment read is base + lane*16B, fully coalesced from global
// AND a linear global_load_lds copy lands in LDS already in fragment order.
__device__ __forceinline__ void frag_decode(long i, int KT, int& m, int& k) {
    int j = (int)(i & 7), r16 = (int)((i >> 3) & 15);
    int quad = (int)((i >> 7) & 3), frag = (int)((i >> 9) & 7);
    long t2 = i >> 12;
    int ktile = (int)(t2 % KT), mtile = (int)(t2 / KT);
    m = mtile * 128 + frag * 16 + r16;
    k = ktile * 32 + quad * 8 + j;
}
__device__ __forceinline__ u16 weff(const float* __restrict__ w, int OC, int Cin, int m, int k) {
    int o = m >> 2, p = m & 3, c = k >> 2, q = k & 3, pq = (p << 2) | q;
    return f2b(c_qsgn[pq] * w[c_qidx[pq] * OC + o * Cin + c]);
}

__global__ void build_weights(const float* __restrict__ wqkv, const float* __restrict__ wproj,
                              const float* __restrict__ wf1, const float* __restrict__ wf2,
                              const float* __restrict__ wpe,
                              u16* __restrict__ Wq, u16* __restrict__ Wp, u16* __restrict__ W1,
                              u16* __restrict__ W2, float* __restrict__ Wpe_eff)
{
    long i = (long)blockIdx.x * 256 + threadIdx.x;
    int m, k;
    if (i < 3145728L) {  // qkv: M=3072 K=1024
        frag_decode(i, 32, m, k);
        Wq[i] = weff(wqkv, 196608, 256, m, k);
        return;
    }
    i -= 3145728L;
    if (i < 1048576L) {  // proj: 1024x1024
        frag_decode(i, 32, m, k);
        Wp[i] = weff(wproj, 65536, 256, m, k);
        return;
    }
    i -= 1048576L;
    if (i < 2097152L) {  // f1: 2048x1024
        frag_decode(i, 32, m, k);
        W1[i] = weff(wf1, 131072, 256, m, k);
        return;
    }
    i -= 2097152L;
    if (i < 2097152L) {  // f2: 1024x2048
        frag_decode(i, 64, m, k);
        W2[i] = weff(wf2, 131072, 512, m, k);
        return;
    }
    i -= 2097152L;
    if (i < 147456L) {   // pe: [g][tap][fi][of], fp32
        int g = (int)(i / 2304), r = (int)(i % 2304);
        int tap = r >> 8, r2 = r & 255;
        int fi = r2 >> 4, of = r2 & 15;
        int ol = of >> 2, p = of & 3, ci = fi >> 2, q = fi & 3, pq = (p << 2) | q;
        Wpe_eff[i] = c_qsgn[pq] * wpe[c_qidx[pq] * 9216 + (g * 4 + ol) * 36 + ci * 9 + tap];
    }
}

__global__ void zero_f(float* __restrict__ a)
{
    a[blockIdx.x * 256 + threadIdx.x] = 0.f;
}

// ------------------------------------------------- cast + transpose of x ---
// x fp32 [b][1024][4096] -> Xt bf16 [b][4096][1024]
__global__ __launch_bounds__(256) void cast_tr(const float* __restrict__ x, u16* __restrict__ Xt)
{
    int b = blockIdx.z, mt = blockIdx.y * 64, nt = blockIdx.x * 64;
    __shared__ u16 tl[64][66];
    int t = threadIdx.x, sub = t >> 4, c4 = (t & 15) * 4;
#pragma unroll
    for (int rr = 0; rr < 4; rr++) {
        int row = rr * 16 + sub;
        float4 v = *(const float4*)(x + ((long)b * 1024 + mt + row) * 4096 + nt + c4);
        uint2 pk;
        pk.x = (unsigned int)f2b(v.x) | ((unsigned int)f2b(v.y) << 16);
        pk.y = (unsigned int)f2b(v.z) | ((unsigned int)f2b(v.w) << 16);
        *(uint2*)(&tl[row][c4]) = pk;
    }
    __syncthreads();
#pragma unroll
    for (int rr = 0; rr < 4; rr++) {
        int row = rr * 16 + sub;
        uint2 o;
        o.x = (unsigned int)tl[c4][row] | ((unsigned int)tl[c4 + 1][row] << 16);
        o.y = (unsigned int)tl[c4 + 2][row] | ((unsigned int)tl[c4 + 3][row] << 16);
        *(uint2*)(Xt + ((long)b * 4096 + nt + row) * 1024 + mt + c4) = o;
    }
}

// ------------------------------------------------------------------ GEMM ---
// 256x256 tile, BK=64, 8 waves (2M x 4N), deep-prefetch 2-barrier schedule
// (best-measured structure, round 3).  A: fragment-ordered linear gl16 copy;
// B: fragment-order gather; all ds_reads lane-contiguous (0 conflicts).
// STATS: epilogue computes per-row (feature) sum / sum-of-squares from the
// fp32 accumulators (16-lane shfl_xor reduce + atomicAdd) -- replaces the
// separate bn_stats / bn_stats_col passes over the output tensor.
__device__ __forceinline__ void gl16(const u16* g, u16* l) {
    __builtin_amdgcn_global_load_lds((gv_t*)g, (lv_t*)l, 16, 0, 0);
}

template<int QM>
__device__ __forceinline__ void load_a(const u16* aS, bf16x8 (&afr)[4][2]) {
#pragma unroll
    for (int f = 0; f < 4; f++)
#pragma unroll
        for (int kk = 0; kk < 2; kk++)
            afr[f][kk] = *(const bf16x8*)(aS + (kk * 8 + QM * 4 + f) * 512);
}
template<int QN>
__device__ __forceinline__ void load_b(const u16* bS, bf16x8 (&bfr)[2][2]) {
#pragma unroll
    for (int g = 0; g < 2; g++)
#pragma unroll
        for (int kk = 0; kk < 2; kk++)
            bfr[g][kk] = *(const bf16x8*)(bS + (QN * 2 + g) * 1024 + kk * 512);
}
template<int QM, int QN>
__device__ __forceinline__ void mf16(const bf16x8 (&afr)[4][2], const bf16x8 (&bfr)[2][2],
                                     f32x4 (&acc)[8][4]) {
    __builtin_amdgcn_s_setprio(1);
#pragma unroll
    for (int f = 0; f < 4; f++)
#pragma unroll
        for (int g = 0; g < 2; g++)
#pragma unroll
            for (int kk = 0; kk < 2; kk++)
                acc[QM * 4 + f][QN * 2 + g] = __builtin_amdgcn_mfma_f32_16x16x32_bf16(
                    afr[f][kk], bfr[g][kk], acc[QM * 4 + f][QN * 2 + g], 0, 0, 0);
    __builtin_amdgcn_s_setprio(0);
}

template<bool TROUT, bool STATS>
__global__ __launch_bounds__(512, 2) void gemm256(
    const u16* __restrict__ A, const u16* __restrict__ Bt, u16* __restrict__ C,
    int M, int N, int K, long strideB, long strideC, float* __restrict__ ST, int Mstat)
{
    __shared__ __align__(16) u16 smem[65536];   // 128 KiB: 2 slots x (A 16384 + B 16384) u16
    const int t = threadIdx.x;
    const int b = blockIdx.z;
    const int m0 = blockIdx.y * 256, n0 = blockIdx.x * 256;
    const int l = t & 63, w = t >> 6;
    const int wr = w >> 2, wc = w & 3;          // wave row (2) x wave col (4)
    const int quad = l >> 4, r16 = l & 15;
    const int KT32 = K >> 5, NT = K >> 6;
    const u16* Bb = Bt + (long)b * strideB;

    // A staging sources (linear copy, 16 KB per half = 2 x 16B per thread)
    const u16* aB0 = A + (long)(2 * blockIdx.y) * KT32 * 4096 + t * 8;
    const u16* aB1 = aB0 + (long)KT32 * 4096;
    // B staging sources (fragment-order gather)
    const int rowS = (w >> 1) * 16 + r16;
    const int colS = (w & 1) * 32 + quad * 8;
    const u16* bB0 = Bb + (long)(n0 + rowS) * K + colS;
    const u16* bB1 = bB0 + (long)128 * K;
    const long bStep = (long)64 * K;

#define STAGE_A(ktv, h) { \
    const u16* s_ = ((h) ? aB1 : aB0) + (long)(ktv) * 8192; \
    u16* d_ = smem + (((ktv) & 1) * 32768) + (h) * 8192 + t * 8; \
    gl16(s_, d_); gl16(s_ + 4096, d_ + 4096); }
#define STAGE_B(ktv, h) { \
    const u16* s_ = ((h) ? bB1 : bB0) + (ktv) * 64; \
    u16* d_ = smem + (((ktv) & 1) * 32768) + 16384 + (h) * 8192 + t * 8; \
    gl16(s_, d_); gl16(s_ + bStep, d_ + 4096); }
#define STAGE_TILE(ktv) { STAGE_A(ktv, 0); STAGE_A(ktv, 1); STAGE_B(ktv, 0); STAGE_B(ktv, 1); }

    // prologue: stage all 4 half-tiles of K-tile 0 into slot 0 (8 loads)
    STAGE_TILE(0);

    f32x4 acc[8][4];
#pragma unroll
    for (int i = 0; i < 8; i++)
#pragma unroll
        for (int j = 0; j < 4; j++) acc[i][j] = (f32x4){0.f, 0.f, 0.f, 0.f};

    for (int kt = 0; kt < NT; ++kt) {
        const int so = (kt & 1) * 32768;
        const u16* aS = smem + so + wr * 8192 + l * 8;
        const u16* bS = smem + so + 16384 + wc * 4096 + l * 8;
        bf16x8 afr[4][2], bfr[2][2];

        if (kt + 1 < NT) {
            STAGE_TILE(kt + 1);                               // 8 loads, slot (kt+1)&1
            asm volatile("s_waitcnt vmcnt(8)" ::: "memory");  // tile kt fully landed
        } else {
            asm volatile("s_waitcnt vmcnt(0)" ::: "memory");
        }
        __builtin_amdgcn_s_barrier();   // publish slot kt&1

        // snake over C quadrants; reads and MFMAs in one region so the
        // compiler can interleave ds_read / MFMA with counted lgkmcnt.
        load_a<0>(aS, afr);
        load_b<0>(bS, bfr);
        mf16<0, 0>(afr, bfr, acc);
        load_b<1>(bS, bfr);
        mf16<0, 1>(afr, bfr, acc);
        load_a<1>(aS, afr);
        mf16<1, 1>(afr, bfr, acc);
        load_b<0>(bS, bfr);
        mf16<1, 0>(afr, bfr, acc);

        __builtin_amdgcn_s_barrier();   // all reads of slot kt&1 done
    }
#undef STAGE_A
#undef STAGE_B
#undef STAGE_TILE

    // --- fused BN statistics: per-row (s, ss) over this block's 256 cols ---
    if constexpr (STATS) {
#pragma unroll
        for (int i = 0; i < 8; i++)
#pragma unroll
            for (int r = 0; r < 4; r++) {
                float s = 0.f, ss = 0.f;
#pragma unroll
                for (int j = 0; j < 4; j++) {
                    float v = acc[i][j][r];
                    s += v; ss += v * v;
                }
#pragma unroll
                for (int o = 1; o < 16; o <<= 1) {   // reduce over r16 lanes
                    s  += __shfl_xor(s, o, 64);
                    ss += __shfl_xor(ss, o, 64);
                }
                if (r16 == 0) {
                    int mm = m0 + wr * 128 + i * 16 + quad * 4 + r;
                    atomicAdd(&ST[mm], s);
                    atomicAdd(&ST[Mstat + mm], ss);
                }
            }
    }

    if (!TROUT) {
        u16* Cb = C + (long)b * strideC;
#pragma unroll
        for (int i = 0; i < 8; i++)
#pragma unroll
            for (int j = 0; j < 4; j++) {
                int mm = m0 + wr * 128 + i * 16 + quad * 4;
                int nn = n0 + wc * 64 + j * 16 + r16;
#pragma unroll
                for (int r = 0; r < 4; r++)
                    Cb[(long)(mm + r) * N + nn] = f2b(acc[i][j][r]);
            }
    } else {
        // pixel-major output C[b][n][m], staged through LDS in two n-halves
        u16* Ct = smem;   // [128][264]
        u16* Cb = C + (long)b * strideC;
#pragma unroll
        for (int h = 0; h < 2; h++) {
            __syncthreads();
            if ((wc >> 1) == h) {
#pragma unroll
                for (int i = 0; i < 8; i++)
#pragma unroll
                    for (int j = 0; j < 4; j++) {
                        int nn = (wc & 1) * 64 + j * 16 + r16;
                        int mm = wr * 128 + i * 16 + quad * 4;
                        ushort4 pk;
                        pk.x = f2b(acc[i][j][0]); pk.y = f2b(acc[i][j][1]);
                        pk.z = f2b(acc[i][j][2]); pk.w = f2b(acc[i][j][3]);
                        *(ushort4*)(Ct + nn * 264 + mm) = pk;
                    }
            }
            __syncthreads();
#pragma unroll
            for (int e = 0; e < 8; e++) {
                int idx = e * 512 + t;
                int n = idx >> 5, m8 = (idx & 31) * 8;
                uint4 v = *(const uint4*)(Ct + n * 264 + m8);
                *(uint4*)(Cb + (long)(n0 + h * 128 + n) * M + m0 + m8) = v;
            }
        }
    }
}

// ------------------------------------------------------------- attention ---
// Phase 1: partial S over 1024-pixel chunks, 512 blocks, atomicAdd reduce.
__global__ __launch_bounds__(256) void attn_s(const u16* __restrict__ QKV, float* __restrict__ S)
{
    const int chunk = blockIdx.x, bhp = blockIdx.y;
    const int bi = bhp >> 5, h = (bhp >> 2) & 7, p = bhp & 3;
    const long rs = 16384;
    const u16* base = QKV + (long)bi * (3072L * 4096) + (long)(h * 384 + p) * 4096;
    const int t = threadIdx.x, l = t & 63, w = t >> 6;
    const int quad = l >> 4, r16 = l & 15;
    __shared__ float Sred[4][32][32];

    f32x4 acc[2][2];
#pragma unroll
    for (int i = 0; i < 2; i++)
#pragma unroll
        for (int j = 0; j < 2; j++) acc[i][j] = (f32x4){0.f, 0.f, 0.f, 0.f};

    const int nb = chunk * 1024 + w * 256 + quad * 8;
    for (int kk = 0; kk < 256; kk += 32) {
        long off = nb + kk;
        bf16x8 q0 = *(const bf16x8*)(base + (long)r16 * rs + off);
        bf16x8 q1 = *(const bf16x8*)(base + (long)(16 + r16) * rs + off);
        bf16x8 k0 = *(const bf16x8*)(base + (long)(32 + r16) * rs + off);
        bf16x8 k1 = *(const bf16x8*)(base + (long)(48 + r16) * rs + off);
        acc[0][0] = __builtin_amdgcn_mfma_f32_16x16x32_bf16(q0, k0, acc[0][0], 0, 0, 0);
        acc[0][1] = __builtin_amdgcn_mfma_f32_16x16x32_bf16(q0, k1, acc[0][1], 0, 0, 0);
        acc[1][0] = __builtin_amdgcn_mfma_f32_16x16x32_bf16(q1, k0, acc[1][0], 0, 0, 0);
        acc[1][1] = __builtin_amdgcn_mfma_f32_16x16x32_bf16(q1, k1, acc[1][1], 0, 0, 0);
    }
#pragma unroll
    for (int i = 0; i < 2; i++)
#pragma unroll
        for (int j = 0; j < 2; j++)
#pragma unroll
            for (int r = 0; r < 4; r++)
                Sred[w][i * 16 + quad * 4 + r][j * 16 + r16] = acc[i][j][r];
    __syncthreads();
    for (int e = t; e < 1024; e += 256) {
        int c = e >> 5, d = e & 31;
        float v = Sred[0][c][d] + Sred[1][c][d] + Sred[2][c][d] + Sred[3][c][d];
        atomicAdd(&S[(long)bhp * 1024 + e], v);
    }
}

// Phase 2: O = P V with fused scale+softmax on the LDS-resident S tile.
// 1024 blocks, 512 pixels each, 2 px/thread.
__global__ __launch_bounds__(256) void attn_pv(const u16* __restrict__ QKV, const float* __restrict__ S,
                                               u16* __restrict__ O)
{
    const int ns = blockIdx.x * 512, bhp = blockIdx.y;
    const int bi = bhp >> 5, h = (bhp >> 2) & 7, p = bhp & 3;
    const long rs = 16384;
    const u16* base = QKV + (long)bi * (3072L * 4096) + (long)(h * 384 + p) * 4096;
    const int t = threadIdx.x;
    __shared__ float Pl[1024];
    for (int e = t; e < 1024; e += 256) Pl[e] = S[(long)bhp * 1024 + e];
    __syncthreads();
    if (t < 32) {   // row-softmax of the 32x32 S tile (tiny; once per block)
        float r[32];
        float mx = -1e30f;
#pragma unroll
        for (int d = 0; d < 32; d++) { r[d] = Pl[t * 32 + d] * 0.17677669529663687f; mx = fmaxf(mx, r[d]); }
        float sum = 0.f;
#pragma unroll
        for (int d = 0; d < 32; d++) { r[d] = __expf(r[d] - mx); sum += r[d]; }
        float inv = 1.f / sum;
#pragma unroll
        for (int d = 0; d < 32; d++) Pl[t * 32 + d] = r[d] * inv;
    }
    __syncthreads();

    float v[32][2];
#pragma unroll
    for (int d = 0; d < 32; d++) {
        unsigned int u = *(const unsigned int*)(base + (long)(64 + d) * rs + ns + 2 * t);
        v[d][0] = b2f((u16)u); v[d][1] = b2f((u16)(u >> 16));
    }
    u16* Ob = O + (long)bi * (1024L * 4096) + (long)(h * 128 + p) * 4096;
    for (int c = 0; c < 32; c++) {
        float s0 = 0.f, s1 = 0.f;
        const float4* prow = (const float4*)(&Pl[c * 32]);
#pragma unroll
        for (int dq = 0; dq < 8; dq++) {
            float4 pv = prow[dq];
            s0 = fmaf(pv.x, v[4*dq+0][0], s0); s1 = fmaf(pv.x, v[4*dq+0][1], s1);
            s0 = fmaf(pv.y, v[4*dq+1][0], s0); s1 = fmaf(pv.y, v[4*dq+1][1], s1);
            s0 = fmaf(pv.z, v[4*dq+2][0], s0); s1 = fmaf(pv.z, v[4*dq+2][1], s1);
            s0 = fmaf(pv.w, v[4*dq+3][0], s0); s1 = fmaf(pv.w, v[4*dq+3][1], s1);
        }
        *(unsigned int*)(Ob + (long)c * 16384 + ns + 2 * t) =
            (unsigned int)f2b(s0) | ((unsigned int)f2b(s1) << 16);
    }
}

// ------------------------------------------------------ pe conv + residual ---
// O2t[b][n][feat] = O + qconv_pe(O)
__global__ __launch_bounds__(256) void pe_kernel(const u16* __restrict__ Oin,
                                                 const float* __restrict__ Wpe,
                                                 u16* __restrict__ O2t)
{
    const int tile = blockIdx.x, g = blockIdx.y, bi = blockIdx.z;
    const int y0 = (tile >> 2) * 16, x0 = (tile & 3) * 16;
    __shared__ float tin[16][324];  // 16 feats x 18x18 halo tile
    const int t = threadIdx.x;
    const u16* Ob = Oin + (long)bi * (1024L * 4096) + (long)(g * 16) * 4096;
    for (int e = t; e < 16 * 324; e += 256) {
        int f = e / 324, rem = e % 324;
        int yy = rem / 18 - 1 + y0, xx = rem % 18 - 1 + x0;
        float v = 0.f;
        if (yy >= 0 && yy < 64 && xx >= 0 && xx < 64)
            v = b2f(Ob[(long)f * 4096 + yy * 64 + xx]);
        tin[f][rem] = v;
    }
    __syncthreads();
    const int y = t >> 4, x = t & 15;
    float acc[16];
#pragma unroll
    for (int of = 0; of < 16; of++) acc[of] = tin[of][(y + 1) * 18 + (x + 1)];  // residual
    const float* Wg = Wpe + g * 2304;
    for (int dy = 0; dy < 3; dy++)
        for (int dx = 0; dx < 3; dx++) {
            int off = (y + dy) * 18 + (x + dx);
            int tap = dy * 3 + dx;
            for (int fi = 0; fi < 16; fi++) {
                float v = tin[fi][off];
                const float* wp = Wg + (tap * 16 + fi) * 16;
#pragma unroll
                for (int of = 0; of < 16; of++) acc[of] = fmaf(wp[of], v, acc[of]);
            }
        }
    long n = (long)(y0 + y) * 64 + (x0 + x);
    unsigned int* op = (unsigned int*)(O2t + ((long)bi * 4096 + n) * 1024 + g * 16);
#pragma unroll
    for (int u = 0; u < 8; u++)
        op[u] = (unsigned int)f2b(acc[2 * u]) | ((unsigned int)f2b(acc[2 * u + 1]) << 16);
}

// ---------------- X1t = cast_tr(x + BN(P)) bf16, stats from raw (s,ss) ------
__global__ __launch_bounds__(256) void bn_add_tr(const float* __restrict__ x, const u16* __restrict__ P,
    const float* __restrict__ ST, const float* __restrict__ gamma, const float* __restrict__ beta,
    u16* __restrict__ X1t)
{
    int b = blockIdx.z, mt = blockIdx.y * 64, nt = blockIdx.x * 64;
    __shared__ u16 tl[64][66];
    int t = threadIdx.x, sub = t >> 4, c4 = (t & 15) * 4;
#pragma unroll
    for (int rr = 0; rr < 4; rr++) {
        int row = rr * 16 + sub, m = mt + row;
        float s = ST[m], ss = ST[1024 + m];
        float mean = s * (1.f / 16384.f);
        float var = ss * (1.f / 16384.f) - mean * mean;
        float gm = gamma[m] * rsqrtf(var + 1e-5f);
        float bs = beta[m] - gm * mean;
        long gi = ((long)b * 1024 + m) * 4096 + nt + c4;
        float4 xv = *(const float4*)(x + gi);
        uint2 pv = *(const uint2*)(P + gi);
        uint2 pk;
        pk.x = (unsigned int)f2b(xv.x + fmaf(gm, b2f((u16)pv.x), bs)) |
               ((unsigned int)f2b(xv.y + fmaf(gm, b2f((u16)(pv.x >> 16)), bs)) << 16);
        pk.y = (unsigned int)f2b(xv.z + fmaf(gm, b2f((u16)pv.y), bs)) |
               ((unsigned int)f2b(xv.w + fmaf(gm, b2f((u16)(pv.y >> 16)), bs)) << 16);
        *(uint2*)(&tl[row][c4]) = pk;
    }
    __syncthreads();
#pragma unroll
    for (int rr = 0; rr < 4; rr++) {
        int row = rr * 16 + sub;
        uint2 o;
        o.x = (unsigned int)tl[c4][row] | ((unsigned int)tl[c4 + 1][row] << 16);
        o.y = (unsigned int)tl[c4 + 2][row] | ((unsigned int)tl[c4 + 3][row] << 16);
        *(uint2*)(X1t + ((long)b * 4096 + nt + row) * 1024 + mt + c4) = o;
    }
}

// --------------------------------- in-place relu(BN(.)) on pixel-major F1 ---
__global__ __launch_bounds__(256) void bn_relu_ip(u16* __restrict__ Xp, const float* __restrict__ accum,
    const float* __restrict__ gamma, const float* __restrict__ beta)
{
    long i = ((long)blockIdx.x * 256 + threadIdx.x) * 8;
    int f = (int)(i & 2047);
    uint4 uv = *(const uint4*)(Xp + i);
    unsigned int wsa[4] = {uv.x, uv.y, uv.z, uv.w};
    unsigned int ov[4];
#pragma unroll
    for (int u = 0; u < 4; u++) {
        unsigned int o = 0;
#pragma unroll
        for (int h = 0; h < 2; h++) {
            int ff = f + 2 * u + h;
            float S = accum[ff], SS = accum[2048 + ff];
            float mean = S * (1.f / 16384.f);
            float var = SS * (1.f / 16384.f) - mean * mean;
            float g = gamma[ff] * rsqrtf(var + 1e-5f);
            float bb = beta[ff] - g * mean;
            float xv = b2f((u16)(wsa[u] >> (16 * h)));
            float v = fmaxf(fmaf(g, xv, bb), 0.f);
            o |= ((unsigned int)f2b(v)) << (16 * h);
        }
        ov[u] = o;
    }
    *(uint4*)(Xp + i) = *(uint4*)ov;
}

// -- out[b][m][n] fp32 = X1t[b][n][m] + BN3(F2[b][m][n]), stats from (s,ss) --
__global__ __launch_bounds__(256) void final_tr(const u16* __restrict__ X1t, const u16* __restrict__ F2,
    const float* __restrict__ ST, const float* __restrict__ gamma, const float* __restrict__ beta,
    float* __restrict__ out)
{
    int b = blockIdx.z, mt = blockIdx.y * 64, nt = blockIdx.x * 64;
    __shared__ u16 tl[64][66];
    int t = threadIdx.x, sub = t >> 4, c4 = (t & 15) * 4;
#pragma unroll
    for (int rr = 0; rr < 4; rr++) {
        int row = rr * 16 + sub;  // pixel index within tile
        uint2 v = *(const uint2*)(X1t + ((long)b * 4096 + nt + row) * 1024 + mt + c4);
        *(uint2*)(&tl[row][c4]) = v;
    }
    __syncthreads();
#pragma unroll
    for (int rr = 0; rr < 4; rr++) {
        int row = rr * 16 + sub, m = mt + row;
        float s = ST[m], ss = ST[1024 + m];
        float mean = s * (1.f / 16384.f);
        float var = ss * (1.f / 16384.f) - mean * mean;
        float gm = gamma[m] * rsqrtf(var + 1e-5f);
        float bs = beta[m] - gm * mean;
        long gi = ((long)b * 1024 + m) * 4096 + nt + c4;
        uint2 f = *(const uint2*)(F2 + gi);
        float4 o;
        o.x = b2f(tl[c4][row])     + fmaf(gm, b2f((u16)f.x), bs);
        o.y = b2f(tl[c4 + 1][row]) + fmaf(gm, b2f((u16)(f.x >> 16)), bs);
        o.z = b2f(tl[c4 + 2][row]) + fmaf(gm, b2f((u16)f.y), bs);
        o.w = b2f(tl[c4 + 3][row]) + fmaf(gm, b2f((u16)(f.y >> 16)), bs);
        *(float4*)(out + gi) = o;
    }
}

extern "C" void kernel_launch(void* const* d_in, const int* in_sizes, int n_in,
                              void* d_out, int out_size, void* d_ws, size_t ws_size,
                              hipStream_t stream)
{
    const float* x     = (const float*)d_in[0];
    const float* wqkv  = (const float*)d_in[1];
    const float* wproj = (const float*)d_in[2];
    const float* wpe   = (const float*)d_in[3];
    const float* g_n   = (const float*)d_in[4];
    const float* b_n   = (const float*)d_in[5];
    const float* wf1   = (const float*)d_in[6];
    const float* g_f1  = (const float*)d_in[7];
    const float* b_f1  = (const float*)d_in[8];
    const float* wf2   = (const float*)d_in[9];
    const float* g_f2  = (const float*)d_in[10];
    const float* b_f2  = (const float*)d_in[11];
    float* out = (float*)d_out;
    char* ws = (char*)d_ws;

    // workspace layout, total 152,141,824 bytes (~145.1 MiB):
    //   [0, 17.4M)        weights (persistent)
    //   [17.4M, 17.9M)    st1(2048f) st3(2048f) accum2(4096f) Sbuf(131072f)
    //                     -- all zeroed by one zero_f (544 blocks)
    //   [17.9M, 118.6M)   QKV -> {O2t,X1t}@17.9M + {P,F1p}@51.5M
    //   [118.6M, 152.1M)  Xt -> Oat -> F2
    u16*   Wq      = (u16*)(ws + 0);
    u16*   Wp      = (u16*)(ws + 6291456);
    u16*   W1      = (u16*)(ws + 8388608);
    u16*   W2      = (u16*)(ws + 12582912);
    float* Wpe_eff = (float*)(ws + 16777216);
    float* st1     = (float*)(ws + 17367040);   // [1024 s][1024 ss]
    float* st3     = (float*)(ws + 17375232);   // [1024 s][1024 ss]
    float* accum2  = (float*)(ws + 17383424);   // [2048 s][2048 ss]
    float* Sbuf    = (float*)(ws + 17399808);   // 128 x 1024 fp32
    float* st_zero = st1;                       // contiguous zero region
    u16*   QKV = (u16*)(ws + 17924096);         // 100.7 MB
    u16*   O2t = (u16*)(ws + 17924096);         // 33.5 MB
    u16*   X1t = (u16*)(ws + 17924096);         // 33.5 MB
    u16*   P   = (u16*)(ws + 51478528);         // 33.5 MB
    u16*   F1p = (u16*)(ws + 51478528);         // 67 MB (pixel-major)
    u16*   Xt  = (u16*)(ws + 118587392);        // 33.5 MB
    u16*   Oat = (u16*)(ws + 118587392);        // 33.5 MB
    u16*   F2  = (u16*)(ws + 118587392);        // 33.5 MB

    zero_f<<<544, 256, 0, stream>>>(st_zero);   // st1+st3+accum2+Sbuf (contiguous)
    build_weights<<<33344, 256, 0, stream>>>(wqkv, wproj, wf1, wf2, wpe, Wq, Wp, W1, W2, Wpe_eff);
    cast_tr<<<dim3(64, 16, 4), 256, 0, stream>>>(x, Xt);
    gemm256<false, false><<<dim3(16, 12, 4), 512, 0, stream>>>(Wq, Xt, QKV, 3072, 4096, 1024, 4096L * 1024, 3072L * 4096, nullptr, 0);
    attn_s<<<dim3(4, 128), 256, 0, stream>>>(QKV, Sbuf);
    attn_pv<<<dim3(8, 128), 256, 0, stream>>>(QKV, Sbuf, Oat);
    pe_kernel<<<dim3(16, 64, 4), 256, 0, stream>>>(Oat, Wpe_eff, O2t);
    gemm256<false, true><<<dim3(16, 4, 4), 512, 0, stream>>>(Wp, O2t, P, 1024, 4096, 1024, 4096L * 1024, 1024L * 4096, st1, 1024);
    bn_add_tr<<<dim3(64, 16, 4), 256, 0, stream>>>(x, P, st1, g_n, b_n, X1t);
    gemm256<true, true><<<dim3(16, 8, 4), 512, 0, stream>>>(W1, X1t, F1p, 2048, 4096, 1024, 4096L * 1024, 4096L * 2048, accum2, 2048);
    bn_relu_ip<<<16384, 256, 0, stream>>>(F1p, accum2, g_f1, b_f1);
    gemm256<false, true><<<dim3(16, 4, 4), 512, 0, stream>>>(W2, F1p, F2, 1024, 4096, 2048, 4096L * 2048, 1024L * 4096, st3, 1024);
    final_tr<<<dim3(64, 16, 4), 256, 0, stream>>>(X1t, F2, st3, g_f2, b_f2, out);
}

// Round 8
// 693.260 us; speedup vs baseline: 1.1366x; 1.1366x over previous
//
#include <hip/hip_runtime.h>

typedef unsigned short u16;
typedef __bf16 bf16x8 __attribute__((ext_vector_type(8)));
typedef float f32x4 __attribute__((ext_vector_type(4)));

typedef const __attribute__((address_space(1))) void gv_t;
typedef __attribute__((address_space(3))) void lv_t;

__device__ __forceinline__ float b2f(u16 u) {
    union { unsigned int i; float f; } v; v.i = ((unsigned int)u) << 16; return v.f;
}
__device__ __forceinline__ u16 f2b(float f) {
    union { unsigned int i; float f; } v; v.f = f;
    unsigned int b = v.i;
    return (u16)((b + 0x7FFFu + ((b >> 16) & 1u)) >> 16);
}

// Hamilton product tables: out component p, input component q -> weight index / sign
__constant__ int   c_qidx[16] = {0,1,2,3, 1,0,3,2, 2,3,0,1, 3,2,1,0};
__constant__ float c_qsgn[16] = {1,-1,-1,-1, 1,1,1,-1, 1,-1,1,1, 1,1,-1,1};

// ---------------------------------------------------------------- weights ---
// GEMM weights stored in MFMA-fragment order:
//   u16 idx = ((((mtile*KT + ktile)*8 + frag)*4 + quad)*16 + r16)*8 + j
// so a wave's A-fragment read is base + lane*16B, fully coalesced from global
// AND a linear global_load_lds copy lands in LDS already in fragment order.
__device__ __forceinline__ void frag_decode(long i, int KT, int& m, int& k) {
    int j = (int)(i & 7), r16 = (int)((i >> 3) & 15);
    int quad = (int)((i >> 7) & 3), frag = (int)((i >> 9) & 7);
    long t2 = i >> 12;
    int ktile = (int)(t2 % KT), mtile = (int)(t2 / KT);
    m = mtile * 128 + frag * 16 + r16;
    k = ktile * 32 + quad * 8 + j;
}
__device__ __forceinline__ u16 weff(const float* __restrict__ w, int OC, int Cin, int m, int k) {
    int o = m >> 2, p = m & 3, c = k >> 2, q = k & 3, pq = (p << 2) | q;
    return f2b(c_qsgn[pq] * w[c_qidx[pq] * OC + o * Cin + c]);
}

__global__ void build_weights(const float* __restrict__ wqkv, const float* __restrict__ wproj,
                              const float* __restrict__ wf1, const float* __restrict__ wf2,
                              const float* __restrict__ wpe,
                              u16* __restrict__ Wq, u16* __restrict__ Wp, u16* __restrict__ W1,
                              u16* __restrict__ W2, float* __restrict__ Wpe_eff)
{
    long i = (long)blockIdx.x * 256 + threadIdx.x;
    int m, k;
    if (i < 3145728L) {  // qkv: M=3072 K=1024
        frag_decode(i, 32, m, k);
        Wq[i] = weff(wqkv, 196608, 256, m, k);
        return;
    }
    i -= 3145728L;
    if (i < 1048576L) {  // proj: 1024x1024
        frag_decode(i, 32, m, k);
        Wp[i] = weff(wproj, 65536, 256, m, k);
        return;
    }
    i -= 1048576L;
    if (i < 2097152L) {  // f1: 2048x1024
        frag_decode(i, 32, m, k);
        W1[i] = weff(wf1, 131072, 256, m, k);
        return;
    }
    i -= 2097152L;
    if (i < 2097152L) {  // f2: 1024x2048
        frag_decode(i, 64, m, k);
        W2[i] = weff(wf2, 131072, 512, m, k);
        return;
    }
    i -= 2097152L;
    if (i < 147456L) {   // pe: [g][tap][fi][of], fp32
        int g = (int)(i / 2304), r = (int)(i % 2304);
        int tap = r >> 8, r2 = r & 255;
        int fi = r2 >> 4, of = r2 & 15;
        int ol = of >> 2, p = of & 3, ci = fi >> 2, q = fi & 3, pq = (p << 2) | q;
        Wpe_eff[i] = c_qsgn[pq] * wpe[c_qidx[pq] * 9216 + (g * 4 + ol) * 36 + ci * 9 + tap];
    }
}

__global__ void zero_f(float* __restrict__ a)
{
    a[blockIdx.x * 256 + threadIdx.x] = 0.f;
}

// ------------------------------------------------- cast + transpose of x ---
// x fp32 [b][1024][4096] -> Xt bf16 [b][4096][1024]
__global__ __launch_bounds__(256) void cast_tr(const float* __restrict__ x, u16* __restrict__ Xt)
{
    int b = blockIdx.z, mt = blockIdx.y * 64, nt = blockIdx.x * 64;
    __shared__ u16 tl[64][66];
    int t = threadIdx.x, sub = t >> 4, c4 = (t & 15) * 4;
#pragma unroll
    for (int rr = 0; rr < 4; rr++) {
        int row = rr * 16 + sub;
        float4 v = *(const float4*)(x + ((long)b * 1024 + mt + row) * 4096 + nt + c4);
        uint2 pk;
        pk.x = (unsigned int)f2b(v.x) | ((unsigned int)f2b(v.y) << 16);
        pk.y = (unsigned int)f2b(v.z) | ((unsigned int)f2b(v.w) << 16);
        *(uint2*)(&tl[row][c4]) = pk;
    }
    __syncthreads();
#pragma unroll
    for (int rr = 0; rr < 4; rr++) {
        int row = rr * 16 + sub;
        uint2 o;
        o.x = (unsigned int)tl[c4][row] | ((unsigned int)tl[c4 + 1][row] << 16);
        o.y = (unsigned int)tl[c4 + 2][row] | ((unsigned int)tl[c4 + 3][row] << 16);
        *(uint2*)(Xt + ((long)b * 4096 + nt + row) * 1024 + mt + c4) = o;
    }
}

// ------------------------------------------------------------------ GEMM ---
// 256x256 tile, BK=64, 8 waves (2M x 4N), m201-style derived-waits 4-phase
// schedule.  Per phase: {ds_read this phase's operands BEFORE the barrier,
// stage ONE half-tile, vmcnt(4) counted (never drained), barrier, lgkmcnt(0)
// + sched_barrier (rule #18), setprio MFMA cluster, barrier}.  Half-tile
// stage positions {B1(kt+1), A1(kt+1), B0(kt+2), A0(kt+2)} give every half a
// 2-phase land-lead and every stage a write-after-last-read slot:
//   B halves last read at P1 (lgkm-complete < bar2(P1)) -> staged P2/P0
//   A halves last read at P2                            -> staged P3/P1
// vmcnt(4) = allow 2 newest halves in flight; induction: after each phase's
// wait, all halves staged >=2 phases ago have landed, so tile kt is fully
// resident before kt's P0 pre-barrier reads (published by kt-1 P3 barrier).
// Tail: stage indices clamped to NT-1 -> duplicate identical-data writes
// (benign) and all addresses stay in the round-3-verified ranges.
__device__ __forceinline__ void gl16(const u16* g, u16* l) {
    __builtin_amdgcn_global_load_lds((gv_t*)g, (lv_t*)l, 16, 0, 0);
}

template<int QM>
__device__ __forceinline__ void load_a(const u16* aS, bf16x8 (&afr)[4][2]) {
#pragma unroll
    for (int f = 0; f < 4; f++)
#pragma unroll
        for (int kk = 0; kk < 2; kk++)
            afr[f][kk] = *(const bf16x8*)(aS + (kk * 8 + QM * 4 + f) * 512);
}
template<int QN>
__device__ __forceinline__ void load_b(const u16* bS, bf16x8 (&bfr)[2][2]) {
#pragma unroll
    for (int g = 0; g < 2; g++)
#pragma unroll
        for (int kk = 0; kk < 2; kk++)
            bfr[g][kk] = *(const bf16x8*)(bS + (QN * 2 + g) * 1024 + kk * 512);
}
template<int QM, int QN>
__device__ __forceinline__ void mf16(const bf16x8 (&afr)[4][2], const bf16x8 (&bfr)[2][2],
                                     f32x4 (&acc)[8][4]) {
    __builtin_amdgcn_s_setprio(1);
#pragma unroll
    for (int f = 0; f < 4; f++)
#pragma unroll
        for (int g = 0; g < 2; g++)
#pragma unroll
            for (int kk = 0; kk < 2; kk++)
                acc[QM * 4 + f][QN * 2 + g] = __builtin_amdgcn_mfma_f32_16x16x32_bf16(
                    afr[f][kk], bfr[g][kk], acc[QM * 4 + f][QN * 2 + g], 0, 0, 0);
    __builtin_amdgcn_s_setprio(0);
}

#define PHASE_SYNC() \
    __builtin_amdgcn_sched_barrier(0); \
    asm volatile("s_waitcnt vmcnt(4)" ::: "memory"); \
    __builtin_amdgcn_s_barrier(); \
    asm volatile("s_waitcnt lgkmcnt(0)" ::: "memory"); \
    __builtin_amdgcn_sched_barrier(0);

template<bool TROUT>
__global__ __launch_bounds__(512, 2) void gemm256(
    const u16* __restrict__ A, const u16* __restrict__ Bt, u16* __restrict__ C,
    int M, int N, int K, long strideB, long strideC)
{
    __shared__ __align__(16) u16 smem[65536];   // 128 KiB: 2 slots x (A 16384 + B 16384) u16
    const int t = threadIdx.x;
    const int b = blockIdx.z;
    const int m0 = blockIdx.y * 256, n0 = blockIdx.x * 256;
    const int l = t & 63, w = t >> 6;
    const int wr = w >> 2, wc = w & 3;          // wave row (2) x wave col (4)
    const int quad = l >> 4, r16 = l & 15;
    const int KT32 = K >> 5, NT = K >> 6;
    const u16* Bb = Bt + (long)b * strideB;

    // A staging sources (linear copy, 16 KB per half = 2 x 16B per thread)
    const u16* aB0 = A + (long)(2 * blockIdx.y) * KT32 * 4096 + t * 8;
    const u16* aB1 = aB0 + (long)KT32 * 4096;
    // B staging sources (fragment-order gather)
    const int rowS = (w >> 1) * 16 + r16;
    const int colS = (w & 1) * 32 + quad * 8;
    const u16* bB0 = Bb + (long)(n0 + rowS) * K + colS;
    const u16* bB1 = bB0 + (long)128 * K;
    const long bStep = (long)64 * K;

    // per-wave LDS read bases (u16 offsets within a slot)
    const int aOff = wr * 8192 + l * 8;
    const int bOff = 16384 + wc * 4096 + l * 8;

#define STAGE_A(ktv, h) { \
    const u16* s_ = ((h) ? aB1 : aB0) + (long)(ktv) * 8192; \
    u16* d_ = smem + (((ktv) & 1) * 32768) + (h) * 8192 + t * 8; \
    gl16(s_, d_); gl16(s_ + 4096, d_ + 4096); }
#define STAGE_B(ktv, h) { \
    const u16* s_ = ((h) ? bB1 : bB0) + (ktv) * 64; \
    u16* d_ = smem + (((ktv) & 1) * 32768) + 16384 + (h) * 8192 + t * 8; \
    gl16(s_, d_); gl16(s_ + bStep, d_ + 4096); }

    f32x4 acc[8][4];
#pragma unroll
    for (int i = 0; i < 8; i++)
#pragma unroll
        for (int j = 0; j < 4; j++) acc[i][j] = (f32x4){0.f, 0.f, 0.f, 0.f};

    bf16x8 RA[4][2], RB0[2][2], RB1[2][2];

    // prologue: tile 0 fully + first two halves of tile 1 (12 loads)
    STAGE_B(0, 0); STAGE_A(0, 0); STAGE_B(0, 1); STAGE_A(0, 1);
    STAGE_B(1, 0); STAGE_A(1, 0);
    asm volatile("s_waitcnt vmcnt(4)" ::: "memory");   // tile 0 landed
    __builtin_amdgcn_s_barrier();

    for (int kt = 0; kt < NT; ++kt) {
        const int so = (kt & 1) * 32768;
        const u16* aS = smem + so + aOff;
        const u16* bS = smem + so + bOff;
        const int k1 = (kt + 1 < NT) ? kt + 1 : NT - 1;
        const int k2 = (kt + 2 < NT) ? kt + 2 : NT - 1;

        // ---- P0 ----
        load_a<0>(aS, RA);          // 8 ds_read_b128
        load_b<0>(bS, RB0);         // 4 ds_read_b128
        STAGE_B(k1, 1);
        PHASE_SYNC();
        mf16<0, 0>(RA, RB0, acc);
        __builtin_amdgcn_s_barrier();
        // ---- P1 ----
        load_b<1>(bS, RB1);
        STAGE_A(k1, 1);
        PHASE_SYNC();
        mf16<0, 1>(RA, RB1, acc);
        __builtin_amdgcn_s_barrier();
        // ---- P2 ----
        load_a<1>(aS, RA);
        STAGE_B(k2, 0);
        PHASE_SYNC();
        mf16<1, 1>(RA, RB1, acc);
        __builtin_amdgcn_s_barrier();
        // ---- P3 ----
        STAGE_A(k2, 0);
        PHASE_SYNC();
        mf16<1, 0>(RA, RB0, acc);
        __builtin_amdgcn_s_barrier();
    }
    asm volatile("s_waitcnt vmcnt(0)" ::: "memory");   // drain ghost stages
    __builtin_amdgcn_s_barrier();
#undef STAGE_A
#undef STAGE_B

    if (!TROUT) {
        u16* Cb = C + (long)b * strideC;
#pragma unroll
        for (int i = 0; i < 8; i++)
#pragma unroll
            for (int j = 0; j < 4; j++) {
                int mm = m0 + wr * 128 + i * 16 + quad * 4;
                int nn = n0 + wc * 64 + j * 16 + r16;
#pragma unroll
                for (int r = 0; r < 4; r++)
                    Cb[(long)(mm + r) * N + nn] = f2b(acc[i][j][r]);
            }
    } else {
        // pixel-major output C[b][n][m], staged through LDS in two n-halves
        u16* Ct = smem;   // [128][264]
        u16* Cb = C + (long)b * strideC;
#pragma unroll
        for (int h = 0; h < 2; h++) {
            __syncthreads();
            if ((wc >> 1) == h) {
#pragma unroll
                for (int i = 0; i < 8; i++)
#pragma unroll
                    for (int j = 0; j < 4; j++) {
                        int nn = (wc & 1) * 64 + j * 16 + r16;
                        int mm = wr * 128 + i * 16 + quad * 4;
                        ushort4 pk;
                        pk.x = f2b(acc[i][j][0]); pk.y = f2b(acc[i][j][1]);
                        pk.z = f2b(acc[i][j][2]); pk.w = f2b(acc[i][j][3]);
                        *(ushort4*)(Ct + nn * 264 + mm) = pk;
                    }
            }
            __syncthreads();
#pragma unroll
            for (int e = 0; e < 8; e++) {
                int idx = e * 512 + t;
                int n = idx >> 5, m8 = (idx & 31) * 8;
                uint4 v = *(const uint4*)(Ct + n * 264 + m8);
                *(uint4*)(Cb + (long)(n0 + h * 128 + n) * M + m0 + m8) = v;
            }
        }
    }
}
#undef PHASE_SYNC

// ------------------------------------------------------------- attention ---
// Phase 1: partial S over 1024-pixel chunks, 512 blocks, atomicAdd reduce.
__global__ __launch_bounds__(256) void attn_s(const u16* __restrict__ QKV, float* __restrict__ S)
{
    const int chunk = blockIdx.x, bhp = blockIdx.y;
    const int bi = bhp >> 5, h = (bhp >> 2) & 7, p = bhp & 3;
    const long rs = 16384;
    const u16* base = QKV + (long)bi * (3072L * 4096) + (long)(h * 384 + p) * 4096;
    const int t = threadIdx.x, l = t & 63, w = t >> 6;
    const int quad = l >> 4, r16 = l & 15;
    __shared__ float Sred[4][32][32];

    f32x4 acc[2][2];
#pragma unroll
    for (int i = 0; i < 2; i++)
#pragma unroll
        for (int j = 0; j < 2; j++) acc[i][j] = (f32x4){0.f, 0.f, 0.f, 0.f};

    const int nb = chunk * 1024 + w * 256 + quad * 8;
    for (int kk = 0; kk < 256; kk += 32) {
        long off = nb + kk;
        bf16x8 q0 = *(const bf16x8*)(base + (long)r16 * rs + off);
        bf16x8 q1 = *(const bf16x8*)(base + (long)(16 + r16) * rs + off);
        bf16x8 k0 = *(const bf16x8*)(base + (long)(32 + r16) * rs + off);
        bf16x8 k1 = *(const bf16x8*)(base + (long)(48 + r16) * rs + off);
        acc[0][0] = __builtin_amdgcn_mfma_f32_16x16x32_bf16(q0, k0, acc[0][0], 0, 0, 0);
        acc[0][1] = __builtin_amdgcn_mfma_f32_16x16x32_bf16(q0, k1, acc[0][1], 0, 0, 0);
        acc[1][0] = __builtin_amdgcn_mfma_f32_16x16x32_bf16(q1, k0, acc[1][0], 0, 0, 0);
        acc[1][1] = __builtin_amdgcn_mfma_f32_16x16x32_bf16(q1, k1, acc[1][1], 0, 0, 0);
    }
#pragma unroll
    for (int i = 0; i < 2; i++)
#pragma unroll
        for (int j = 0; j < 2; j++)
#pragma unroll
            for (int r = 0; r < 4; r++)
                Sred[w][i * 16 + quad * 4 + r][j * 16 + r16] = acc[i][j][r];
    __syncthreads();
    for (int e = t; e < 1024; e += 256) {
        int c = e >> 5, d = e & 31;
        float v = Sred[0][c][d] + Sred[1][c][d] + Sred[2][c][d] + Sred[3][c][d];
        atomicAdd(&S[(long)bhp * 1024 + e], v);
    }
}

// Phase 2: O = P V with fused scale+softmax on the LDS-resident S tile.
// 1024 blocks, 512 pixels each, 2 px/thread.
__global__ __launch_bounds__(256) void attn_pv(const u16* __restrict__ QKV, const float* __restrict__ S,
                                               u16* __restrict__ O)
{
    const int ns = blockIdx.x * 512, bhp = blockIdx.y;
    const int bi = bhp >> 5, h = (bhp >> 2) & 7, p = bhp & 3;
    const long rs = 16384;
    const u16* base = QKV + (long)bi * (3072L * 4096) + (long)(h * 384 + p) * 4096;
    const int t = threadIdx.x;
    __shared__ float Pl[1024];
    for (int e = t; e < 1024; e += 256) Pl[e] = S[(long)bhp * 1024 + e];
    __syncthreads();
    if (t < 32) {   // row-softmax of the 32x32 S tile (tiny; once per block)
        float r[32];
        float mx = -1e30f;
#pragma unroll
        for (int d = 0; d < 32; d++) { r[d] = Pl[t * 32 + d] * 0.17677669529663687f; mx = fmaxf(mx, r[d]); }
        float sum = 0.f;
#pragma unroll
        for (int d = 0; d < 32; d++) { r[d] = __expf(r[d] - mx); sum += r[d]; }
        float inv = 1.f / sum;
#pragma unroll
        for (int d = 0; d < 32; d++) Pl[t * 32 + d] = r[d] * inv;
    }
    __syncthreads();

    float v[32][2];
#pragma unroll
    for (int d = 0; d < 32; d++) {
        unsigned int u = *(const unsigned int*)(base + (long)(64 + d) * rs + ns + 2 * t);
        v[d][0] = b2f((u16)u); v[d][1] = b2f((u16)(u >> 16));
    }
    u16* Ob = O + (long)bi * (1024L * 4096) + (long)(h * 128 + p) * 4096;
    for (int c = 0; c < 32; c++) {
        float s0 = 0.f, s1 = 0.f;
        const float4* prow = (const float4*)(&Pl[c * 32]);
#pragma unroll
        for (int dq = 0; dq < 8; dq++) {
            float4 pv = prow[dq];
            s0 = fmaf(pv.x, v[4*dq+0][0], s0); s1 = fmaf(pv.x, v[4*dq+0][1], s1);
            s0 = fmaf(pv.y, v[4*dq+1][0], s0); s1 = fmaf(pv.y, v[4*dq+1][1], s1);
            s0 = fmaf(pv.z, v[4*dq+2][0], s0); s1 = fmaf(pv.z, v[4*dq+2][1], s1);
            s0 = fmaf(pv.w, v[4*dq+3][0], s0); s1 = fmaf(pv.w, v[4*dq+3][1], s1);
        }
        *(unsigned int*)(Ob + (long)c * 16384 + ns + 2 * t) =
            (unsigned int)f2b(s0) | ((unsigned int)f2b(s1) << 16);
    }
}

// ------------------------------------------------------ pe conv + residual ---
// O2t[b][n][feat] = O + qconv_pe(O)
__global__ __launch_bounds__(256) void pe_kernel(const u16* __restrict__ Oin,
                                                 const float* __restrict__ Wpe,
                                                 u16* __restrict__ O2t)
{
    const int tile = blockIdx.x, g = blockIdx.y, bi = blockIdx.z;
    const int y0 = (tile >> 2) * 16, x0 = (tile & 3) * 16;
    __shared__ float tin[16][324];  // 16 feats x 18x18 halo tile
    const int t = threadIdx.x;
    const u16* Ob = Oin + (long)bi * (1024L * 4096) + (long)(g * 16) * 4096;
    for (int e = t; e < 16 * 324; e += 256) {
        int f = e / 324, rem = e % 324;
        int yy = rem / 18 - 1 + y0, xx = rem % 18 - 1 + x0;
        float v = 0.f;
        if (yy >= 0 && yy < 64 && xx >= 0 && xx < 64)
            v = b2f(Ob[(long)f * 4096 + yy * 64 + xx]);
        tin[f][rem] = v;
    }
    __syncthreads();
    const int y = t >> 4, x = t & 15;
    float acc[16];
#pragma unroll
    for (int of = 0; of < 16; of++) acc[of] = tin[of][(y + 1) * 18 + (x + 1)];  // residual
    const float* Wg = Wpe + g * 2304;
    for (int dy = 0; dy < 3; dy++)
        for (int dx = 0; dx < 3; dx++) {
            int off = (y + dy) * 18 + (x + dx);
            int tap = dy * 3 + dx;
            for (int fi = 0; fi < 16; fi++) {
                float v = tin[fi][off];
                const float* wp = Wg + (tap * 16 + fi) * 16;
#pragma unroll
                for (int of = 0; of < 16; of++) acc[of] = fmaf(wp[of], v, acc[of]);
            }
        }
    long n = (long)(y0 + y) * 64 + (x0 + x);
    unsigned int* op = (unsigned int*)(O2t + ((long)bi * 4096 + n) * 1024 + g * 16);
#pragma unroll
    for (int u = 0; u < 8; u++)
        op[u] = (unsigned int)f2b(acc[2 * u]) | ((unsigned int)f2b(acc[2 * u + 1]) << 16);
}

// ----------------------------------------- BN stats, feature-major layout ---
__global__ __launch_bounds__(256) void bn_stats(const u16* __restrict__ X, float* __restrict__ stats, int M)
{
    const int m = blockIdx.x, t = threadIdx.x;
    float s = 0.f, ss = 0.f;
    for (int b = 0; b < 4; b++) {
        const u16* rowp = X + ((long)b * M + m) * 4096;
        for (int pass = 0; pass < 2; pass++) {
            uint4 uv = *(const uint4*)(rowp + pass * 2048 + t * 8);
            unsigned int wsa[4] = {uv.x, uv.y, uv.z, uv.w};
#pragma unroll
            for (int u = 0; u < 4; u++) {
                float v0 = b2f((u16)wsa[u]), v1 = b2f((u16)(wsa[u] >> 16));
                s += v0 + v1; ss += v0 * v0 + v1 * v1;
            }
        }
    }
    __shared__ float rs[4], rss[4];
    for (int o = 32; o > 0; o >>= 1) { s += __shfl_down(s, o); ss += __shfl_down(ss, o); }
    if ((t & 63) == 0) { rs[t >> 6] = s; rss[t >> 6] = ss; }
    __syncthreads();
    if (t == 0) {
        float S = rs[0] + rs[1] + rs[2] + rs[3];
        float SS = rss[0] + rss[1] + rss[2] + rss[3];
        float mean = S * (1.f / 16384.f);
        float var = SS * (1.f / 16384.f) - mean * mean;
        stats[2 * m] = mean;
        stats[2 * m + 1] = rsqrtf(var + 1e-5f);
    }
}

// ------------------------------------------- X1t = cast_tr(x + BN(P)) bf16 ---
__global__ __launch_bounds__(256) void bn_add_tr(const float* __restrict__ x, const u16* __restrict__ P,
    const float* __restrict__ stats, const float* __restrict__ gamma, const float* __restrict__ beta,
    u16* __restrict__ X1t)
{
    int b = blockIdx.z, mt = blockIdx.y * 64, nt = blockIdx.x * 64;
    __shared__ u16 tl[64][66];
    int t = threadIdx.x, sub = t >> 4, c4 = (t & 15) * 4;
#pragma unroll
    for (int rr = 0; rr < 4; rr++) {
        int row = rr * 16 + sub, m = mt + row;
        float gm = gamma[m] * stats[2 * m + 1];
        float bs = beta[m] - gm * stats[2 * m];
        long gi = ((long)b * 1024 + m) * 4096 + nt + c4;
        float4 xv = *(const float4*)(x + gi);
        uint2 pv = *(const uint2*)(P + gi);
        uint2 pk;
        pk.x = (unsigned int)f2b(xv.x + fmaf(gm, b2f((u16)pv.x), bs)) |
               ((unsigned int)f2b(xv.y + fmaf(gm, b2f((u16)(pv.x >> 16)), bs)) << 16);
        pk.y = (unsigned int)f2b(xv.z + fmaf(gm, b2f((u16)pv.y), bs)) |
               ((unsigned int)f2b(xv.w + fmaf(gm, b2f((u16)(pv.y >> 16)), bs)) << 16);
        *(uint2*)(&tl[row][c4]) = pk;
    }
    __syncthreads();
#pragma unroll
    for (int rr = 0; rr < 4; rr++) {
        int row = rr * 16 + sub;
        uint2 o;
        o.x = (unsigned int)tl[c4][row] | ((unsigned int)tl[c4 + 1][row] << 16);
        o.y = (unsigned int)tl[c4 + 2][row] | ((unsigned int)tl[c4 + 3][row] << 16);
        *(uint2*)(X1t + ((long)b * 4096 + nt + row) * 1024 + mt + c4) = o;
    }
}

// ----------------------------- BN stats over pixel-major [16384][2048] bf16 ---
__global__ __launch_bounds__(256) void bn_stats_col(const u16* __restrict__ Xp, float* __restrict__ accum)
{
    const int t = threadIdx.x;
    const int f0 = t * 8;
    float s[8], ss[8];
#pragma unroll
    for (int u = 0; u < 8; u++) { s[u] = 0.f; ss[u] = 0.f; }
    const u16* base = Xp + (long)blockIdx.x * 128 * 2048;
    for (int r = 0; r < 128; r++) {
        uint4 uv = *(const uint4*)(base + (long)r * 2048 + f0);
        unsigned int wsa[4] = {uv.x, uv.y, uv.z, uv.w};
#pragma unroll
        for (int u = 0; u < 4; u++) {
            float v0 = b2f((u16)wsa[u]), v1 = b2f((u16)(wsa[u] >> 16));
            s[2*u] += v0;   ss[2*u]   += v0 * v0;
            s[2*u+1] += v1; ss[2*u+1] += v1 * v1;
        }
    }
#pragma unroll
    for (int u = 0; u < 8; u++) {
        atomicAdd(&accum[f0 + u], s[u]);
        atomicAdd(&accum[2048 + f0 + u], ss[u]);
    }
}

// --------------------------------- in-place relu(BN(.)) on pixel-major F1 ---
__global__ __launch_bounds__(256) void bn_relu_ip(u16* __restrict__ Xp, const float* __restrict__ accum,
    const float* __restrict__ gamma, const float* __restrict__ beta)
{
    long i = ((long)blockIdx.x * 256 + threadIdx.x) * 8;
    int f = (int)(i & 2047);
    uint4 uv = *(const uint4*)(Xp + i);
    unsigned int wsa[4] = {uv.x, uv.y, uv.z, uv.w};
    unsigned int ov[4];
#pragma unroll
    for (int u = 0; u < 4; u++) {
        unsigned int o = 0;
#pragma unroll
        for (int h = 0; h < 2; h++) {
            int ff = f + 2 * u + h;
            float S = accum[ff], SS = accum[2048 + ff];
            float mean = S * (1.f / 16384.f);
            float var = SS * (1.f / 16384.f) - mean * mean;
            float g = gamma[ff] * rsqrtf(var + 1e-5f);
            float bb = beta[ff] - g * mean;
            float xv = b2f((u16)(wsa[u] >> (16 * h)));
            float v = fmaxf(fmaf(g, xv, bb), 0.f);
            o |= ((unsigned int)f2b(v)) << (16 * h);
        }
        ov[u] = o;
    }
    *(uint4*)(Xp + i) = *(uint4*)ov;
}

// ---------------------- out[b][m][n] fp32 = X1t[b][n][m] + BN3(F2[b][m][n]) ---
__global__ __launch_bounds__(256) void final_tr(const u16* __restrict__ X1t, const u16* __restrict__ F2,
    const float* __restrict__ stats, const float* __restrict__ gamma, const float* __restrict__ beta,
    float* __restrict__ out)
{
    int b = blockIdx.z, mt = blockIdx.y * 64, nt = blockIdx.x * 64;
    __shared__ u16 tl[64][66];
    int t = threadIdx.x, sub = t >> 4, c4 = (t & 15) * 4;
#pragma unroll
    for (int rr = 0; rr < 4; rr++) {
        int row = rr * 16 + sub;  // pixel index within tile
        uint2 v = *(const uint2*)(X1t + ((long)b * 4096 + nt + row) * 1024 + mt + c4);
        *(uint2*)(&tl[row][c4]) = v;
    }
    __syncthreads();
#pragma unroll
    for (int rr = 0; rr < 4; rr++) {
        int row = rr * 16 + sub, m = mt + row;
        float gm = gamma[m] * stats[2 * m + 1];
        float bs = beta[m] - gm * stats[2 * m];
        long gi = ((long)b * 1024 + m) * 4096 + nt + c4;
        uint2 f = *(const uint2*)(F2 + gi);
        float4 o;
        o.x = b2f(tl[c4][row])     + fmaf(gm, b2f((u16)f.x), bs);
        o.y = b2f(tl[c4 + 1][row]) + fmaf(gm, b2f((u16)(f.x >> 16)), bs);
        o.z = b2f(tl[c4 + 2][row]) + fmaf(gm, b2f((u16)f.y), bs);
        o.w = b2f(tl[c4 + 3][row]) + fmaf(gm, b2f((u16)(f.y >> 16)), bs);
        *(float4*)(out + gi) = o;
    }
}

extern "C" void kernel_launch(void* const* d_in, const int* in_sizes, int n_in,
                              void* d_out, int out_size, void* d_ws, size_t ws_size,
                              hipStream_t stream)
{
    const float* x     = (const float*)d_in[0];
    const float* wqkv  = (const float*)d_in[1];
    const float* wproj = (const float*)d_in[2];
    const float* wpe   = (const float*)d_in[3];
    const float* g_n   = (const float*)d_in[4];
    const float* b_n   = (const float*)d_in[5];
    const float* wf1   = (const float*)d_in[6];
    const float* g_f1  = (const float*)d_in[7];
    const float* b_f1  = (const float*)d_in[8];
    const float* wf2   = (const float*)d_in[9];
    const float* g_f2  = (const float*)d_in[10];
    const float* b_f2  = (const float*)d_in[11];
    float* out = (float*)d_out;
    char* ws = (char*)d_ws;

    // workspace layout, total 152,141,824 bytes (~145.1 MiB):
    //   [0, 17.4M)        weights (persistent)
    //   [17.4M, 17.9M)    st1 | accum2+S (zeroed together) | st3
    //   [17.9M, 118.6M)   QKV -> {O2t,X1t}@17.9M + {P,F1p}@51.5M
    //   [118.6M, 152.1M)  Xt -> Oat -> F2
    u16*   Wq      = (u16*)(ws + 0);
    u16*   Wp      = (u16*)(ws + 6291456);
    u16*   W1      = (u16*)(ws + 8388608);
    u16*   W2      = (u16*)(ws + 12582912);
    float* Wpe_eff = (float*)(ws + 16777216);
    float* st1     = (float*)(ws + 17367040);
    float* accum2  = (float*)(ws + 17375232);   // 4096 floats, then S 131072 floats
    float* Sbuf    = (float*)(ws + 17391616);   // 128 x 1024 fp32
    float* st3     = (float*)(ws + 17915904);
    u16*   QKV = (u16*)(ws + 17924096);         // 100.7 MB
    u16*   O2t = (u16*)(ws + 17924096);         // 33.5 MB
    u16*   X1t = (u16*)(ws + 17924096);         // 33.5 MB
    u16*   P   = (u16*)(ws + 51478528);         // 33.5 MB
    u16*   F1p = (u16*)(ws + 51478528);         // 67 MB (pixel-major)
    u16*   Xt  = (u16*)(ws + 118587392);        // 33.5 MB
    u16*   Oat = (u16*)(ws + 118587392);        // 33.5 MB
    u16*   F2  = (u16*)(ws + 118587392);        // 33.5 MB

    zero_f<<<528, 256, 0, stream>>>(accum2);    // accum2 + Sbuf (contiguous)
    build_weights<<<33344, 256, 0, stream>>>(wqkv, wproj, wf1, wf2, wpe, Wq, Wp, W1, W2, Wpe_eff);
    cast_tr<<<dim3(64, 16, 4), 256, 0, stream>>>(x, Xt);
    gemm256<false><<<dim3(16, 12, 4), 512, 0, stream>>>(Wq, Xt, QKV, 3072, 4096, 1024, 4096L * 1024, 3072L * 4096);
    attn_s<<<dim3(4, 128), 256, 0, stream>>>(QKV, Sbuf);
    attn_pv<<<dim3(8, 128), 256, 0, stream>>>(QKV, Sbuf, Oat);
    pe_kernel<<<dim3(16, 64, 4), 256, 0, stream>>>(Oat, Wpe_eff, O2t);
    gemm256<false><<<dim3(16, 4, 4), 512, 0, stream>>>(Wp, O2t, P, 1024, 4096, 1024, 4096L * 1024, 1024L * 4096);
    bn_stats<<<1024, 256, 0, stream>>>(P, st1, 1024);
    bn_add_tr<<<dim3(64, 16, 4), 256, 0, stream>>>(x, P, st1, g_n, b_n, X1t);
    gemm256<true><<<dim3(16, 8, 4), 512, 0, stream>>>(W1, X1t, F1p, 2048, 4096, 1024, 4096L * 1024, 4096L * 2048);
    bn_stats_col<<<128, 256, 0, stream>>>(F1p, accum2);
    bn_relu_ip<<<16384, 256, 0, stream>>>(F1p, accum2, g_f1, b_f1);
    gemm256<false><<<dim3(16, 4, 4), 512, 0, stream>>>(W2, F1p, F2, 1024, 4096, 2048, 4096L * 2048, 1024L * 4096);
    bn_stats<<<1024, 256, 0, stream>>>(F2, st3, 1024);
    final_tr<<<dim3(64, 16, 4), 256, 0, stream>>>(X1t, F2, st3, g_f2, b_f2, out);
}

// Round 9
// 606.225 us; speedup vs baseline: 1.2998x; 1.1436x over previous
//
#include <hip/hip_runtime.h>

typedef unsigned short u16;
typedef __bf16 bf16x8 __attribute__((ext_vector_type(8)));
typedef float f32x4 __attribute__((ext_vector_type(4)));

typedef const __attribute__((address_space(1))) void gv_t;
typedef __attribute__((address_space(3))) void lv_t;

__device__ __forceinline__ float b2f(u16 u) {
    union { unsigned int i; float f; } v; v.i = ((unsigned int)u) << 16; return v.f;
}
__device__ __forceinline__ u16 f2b(float f) {
    union { unsigned int i; float f; } v; v.f = f;
    unsigned int b = v.i;
    return (u16)((b + 0x7FFFu + ((b >> 16) & 1u)) >> 16);
}

// Hamilton product tables: out component p, input component q -> weight index / sign
__constant__ int   c_qidx[16] = {0,1,2,3, 1,0,3,2, 2,3,0,1, 3,2,1,0};
__constant__ float c_qsgn[16] = {1,-1,-1,-1, 1,1,1,-1, 1,-1,1,1, 1,1,-1,1};

// ---------------------------------------------------------------- weights ---
// GEMM weights stored in MFMA-fragment order:
//   u16 idx = ((((mtile*KT + ktile)*8 + frag)*4 + quad)*16 + r16)*8 + j
__device__ __forceinline__ void frag_decode(long i, int KT, int& m, int& k) {
    int j = (int)(i & 7), r16 = (int)((i >> 3) & 15);
    int quad = (int)((i >> 7) & 3), frag = (int)((i >> 9) & 7);
    long t2 = i >> 12;
    int ktile = (int)(t2 % KT), mtile = (int)(t2 / KT);
    m = mtile * 128 + frag * 16 + r16;
    k = ktile * 32 + quad * 8 + j;
}
__device__ __forceinline__ u16 weff(const float* __restrict__ w, int OC, int Cin, int m, int k) {
    int o = m >> 2, p = m & 3, c = k >> 2, q = k & 3, pq = (p << 2) | q;
    return f2b(c_qsgn[pq] * w[c_qidx[pq] * OC + o * Cin + c]);
}

// ----------------------------------------------------------- fused prologue ---
// blocks [0,528):       zero accum2+Sbuf
// blocks [528,33936):   build GEMM weights (fragment order) + pe MFMA weights
// blocks [33936,38032): cast+transpose x -> Xt
// The three jobs are independent; merging overlaps gather-latency-bound weight
// building with BW-bound cast and removes two launch gaps.
__global__ __launch_bounds__(256) void prologue(
    const float* __restrict__ x,
    const float* __restrict__ wqkv, const float* __restrict__ wproj,
    const float* __restrict__ wf1, const float* __restrict__ wf2,
    const float* __restrict__ wpe,
    float* __restrict__ zbuf,
    u16* __restrict__ Wq, u16* __restrict__ Wp, u16* __restrict__ W1,
    u16* __restrict__ W2, u16* __restrict__ Wpe16,
    u16* __restrict__ Xt)
{
    const int bid = blockIdx.x;
    const int t = threadIdx.x;
    __shared__ u16 tl[64][66];

    if (bid < 528) {                      // ---- zero job
        zbuf[bid * 256 + t] = 0.f;
        return;
    }
    if (bid < 33936) {                    // ---- weight-build job
        long i = (long)(bid - 528) * 256 + t;
        int m, k;
        if (i < 3145728L) {  // qkv: M=3072 K=1024
            frag_decode(i, 32, m, k);
            Wq[i] = weff(wqkv, 196608, 256, m, k);
            return;
        }
        i -= 3145728L;
        if (i < 1048576L) {  // proj: 1024x1024
            frag_decode(i, 32, m, k);
            Wp[i] = weff(wproj, 65536, 256, m, k);
            return;
        }
        i -= 1048576L;
        if (i < 2097152L) {  // f1: 2048x1024
            frag_decode(i, 32, m, k);
            W1[i] = weff(wf1, 131072, 256, m, k);
            return;
        }
        i -= 2097152L;
        if (i < 2097152L) {  // f2: 1024x2048
            frag_decode(i, 64, m, k);
            W2[i] = weff(wf2, 131072, 512, m, k);
            return;
        }
        i -= 2097152L;
        if (i < 163840L) {   // pe MFMA A-frags: idx=(((g*5+kt)*4+quad)*16+of)*8+j
            int j = (int)(i & 7), of = (int)((i >> 3) & 15);
            int quad = (int)((i >> 7) & 3);
            int blk = (int)(i >> 9);            // 0..319
            int kt = blk % 5, g = blk / 5;
            int kk = kt * 32 + quad * 8 + j;    // contraction index 0..159
            int tap = kk >> 4, fi = kk & 15;
            u16 val = 0;
            if (tap < 9) {
                int ol = of >> 2, p = of & 3, ci = fi >> 2, q = fi & 3;
                int pq = (p << 2) | q;
                val = f2b(c_qsgn[pq] * wpe[c_qidx[pq] * 9216 + (g * 4 + ol) * 36 + ci * 9 + tap]);
            }
            Wpe16[i] = val;
        }
        return;
    }
    // ---- cast+transpose job: x fp32 [b][1024][4096] -> Xt bf16 [b][4096][1024]
    int c = bid - 33936;
    int b = c >> 10, mt = ((c >> 6) & 15) * 64, nt = (c & 63) * 64;
    int sub = t >> 4, c4 = (t & 15) * 4;
#pragma unroll
    for (int rr = 0; rr < 4; rr++) {
        int row = rr * 16 + sub;
        float4 v = *(const float4*)(x + ((long)b * 1024 + mt + row) * 4096 + nt + c4);
        uint2 pk;
        pk.x = (unsigned int)f2b(v.x) | ((unsigned int)f2b(v.y) << 16);
        pk.y = (unsigned int)f2b(v.z) | ((unsigned int)f2b(v.w) << 16);
        *(uint2*)(&tl[row][c4]) = pk;
    }
    __syncthreads();
#pragma unroll
    for (int rr = 0; rr < 4; rr++) {
        int row = rr * 16 + sub;
        uint2 o;
        o.x = (unsigned int)tl[c4][row] | ((unsigned int)tl[c4 + 1][row] << 16);
        o.y = (unsigned int)tl[c4 + 2][row] | ((unsigned int)tl[c4 + 3][row] << 16);
        *(uint2*)(Xt + ((long)b * 4096 + nt + row) * 1024 + mt + c4) = o;
    }
}

// ------------------------------------------------------------------ GEMM ---
// 256x256 tile, BK=64, 8 waves (2M x 4N), m201-style derived-waits 4-phase
// schedule (round-8 best: 120 us/36% -- structural plateau, kept frozen).
__device__ __forceinline__ void gl16(const u16* g, u16* l) {
    __builtin_amdgcn_global_load_lds((gv_t*)g, (lv_t*)l, 16, 0, 0);
}

template<int QM>
__device__ __forceinline__ void load_a(const u16* aS, bf16x8 (&afr)[4][2]) {
#pragma unroll
    for (int f = 0; f < 4; f++)
#pragma unroll
        for (int kk = 0; kk < 2; kk++)
            afr[f][kk] = *(const bf16x8*)(aS + (kk * 8 + QM * 4 + f) * 512);
}
template<int QN>
__device__ __forceinline__ void load_b(const u16* bS, bf16x8 (&bfr)[2][2]) {
#pragma unroll
    for (int g = 0; g < 2; g++)
#pragma unroll
        for (int kk = 0; kk < 2; kk++)
            bfr[g][kk] = *(const bf16x8*)(bS + (QN * 2 + g) * 1024 + kk * 512);
}
template<int QM, int QN>
__device__ __forceinline__ void mf16(const bf16x8 (&afr)[4][2], const bf16x8 (&bfr)[2][2],
                                     f32x4 (&acc)[8][4]) {
    __builtin_amdgcn_s_setprio(1);
#pragma unroll
    for (int f = 0; f < 4; f++)
#pragma unroll
        for (int g = 0; g < 2; g++)
#pragma unroll
            for (int kk = 0; kk < 2; kk++)
                acc[QM * 4 + f][QN * 2 + g] = __builtin_amdgcn_mfma_f32_16x16x32_bf16(
                    afr[f][kk], bfr[g][kk], acc[QM * 4 + f][QN * 2 + g], 0, 0, 0);
    __builtin_amdgcn_s_setprio(0);
}

#define PHASE_SYNC() \
    __builtin_amdgcn_sched_barrier(0); \
    asm volatile("s_waitcnt vmcnt(4)" ::: "memory"); \
    __builtin_amdgcn_s_barrier(); \
    asm volatile("s_waitcnt lgkmcnt(0)" ::: "memory"); \
    __builtin_amdgcn_sched_barrier(0);

template<bool TROUT>
__global__ __launch_bounds__(512, 2) void gemm256(
    const u16* __restrict__ A, const u16* __restrict__ Bt, u16* __restrict__ C,
    int M, int N, int K, long strideB, long strideC)
{
    __shared__ __align__(16) u16 smem[65536];   // 128 KiB: 2 slots x (A 16384 + B 16384) u16
    const int t = threadIdx.x;
    const int b = blockIdx.z;
    const int m0 = blockIdx.y * 256, n0 = blockIdx.x * 256;
    const int l = t & 63, w = t >> 6;
    const int wr = w >> 2, wc = w & 3;          // wave row (2) x wave col (4)
    const int quad = l >> 4, r16 = l & 15;
    const int KT32 = K >> 5, NT = K >> 6;
    const u16* Bb = Bt + (long)b * strideB;

    const u16* aB0 = A + (long)(2 * blockIdx.y) * KT32 * 4096 + t * 8;
    const u16* aB1 = aB0 + (long)KT32 * 4096;
    const int rowS = (w >> 1) * 16 + r16;
    const int colS = (w & 1) * 32 + quad * 8;
    const u16* bB0 = Bb + (long)(n0 + rowS) * K + colS;
    const u16* bB1 = bB0 + (long)128 * K;
    const long bStep = (long)64 * K;

    const int aOff = wr * 8192 + l * 8;
    const int bOff = 16384 + wc * 4096 + l * 8;

#define STAGE_A(ktv, h) { \
    const u16* s_ = ((h) ? aB1 : aB0) + (long)(ktv) * 8192; \
    u16* d_ = smem + (((ktv) & 1) * 32768) + (h) * 8192 + t * 8; \
    gl16(s_, d_); gl16(s_ + 4096, d_ + 4096); }
#define STAGE_B(ktv, h) { \
    const u16* s_ = ((h) ? bB1 : bB0) + (ktv) * 64; \
    u16* d_ = smem + (((ktv) & 1) * 32768) + 16384 + (h) * 8192 + t * 8; \
    gl16(s_, d_); gl16(s_ + bStep, d_ + 4096); }

    f32x4 acc[8][4];
#pragma unroll
    for (int i = 0; i < 8; i++)
#pragma unroll
        for (int j = 0; j < 4; j++) acc[i][j] = (f32x4){0.f, 0.f, 0.f, 0.f};

    bf16x8 RA[4][2], RB0[2][2], RB1[2][2];

    STAGE_B(0, 0); STAGE_A(0, 0); STAGE_B(0, 1); STAGE_A(0, 1);
    STAGE_B(1, 0); STAGE_A(1, 0);
    asm volatile("s_waitcnt vmcnt(4)" ::: "memory");   // tile 0 landed
    __builtin_amdgcn_s_barrier();

    for (int kt = 0; kt < NT; ++kt) {
        const int so = (kt & 1) * 32768;
        const u16* aS = smem + so + aOff;
        const u16* bS = smem + so + bOff;
        const int k1 = (kt + 1 < NT) ? kt + 1 : NT - 1;
        const int k2 = (kt + 2 < NT) ? kt + 2 : NT - 1;

        // ---- P0 ----
        load_a<0>(aS, RA);
        load_b<0>(bS, RB0);
        STAGE_B(k1, 1);
        PHASE_SYNC();
        mf16<0, 0>(RA, RB0, acc);
        __builtin_amdgcn_s_barrier();
        // ---- P1 ----
        load_b<1>(bS, RB1);
        STAGE_A(k1, 1);
        PHASE_SYNC();
        mf16<0, 1>(RA, RB1, acc);
        __builtin_amdgcn_s_barrier();
        // ---- P2 ----
        load_a<1>(aS, RA);
        STAGE_B(k2, 0);
        PHASE_SYNC();
        mf16<1, 1>(RA, RB1, acc);
        __builtin_amdgcn_s_barrier();
        // ---- P3 ----
        STAGE_A(k2, 0);
        PHASE_SYNC();
        mf16<1, 0>(RA, RB0, acc);
        __builtin_amdgcn_s_barrier();
    }
    asm volatile("s_waitcnt vmcnt(0)" ::: "memory");   // drain ghost stages
    __builtin_amdgcn_s_barrier();
#undef STAGE_A
#undef STAGE_B

    if (!TROUT) {
        u16* Cb = C + (long)b * strideC;
#pragma unroll
        for (int i = 0; i < 8; i++)
#pragma unroll
            for (int j = 0; j < 4; j++) {
                int mm = m0 + wr * 128 + i * 16 + quad * 4;
                int nn = n0 + wc * 64 + j * 16 + r16;
#pragma unroll
                for (int r = 0; r < 4; r++)
                    Cb[(long)(mm + r) * N + nn] = f2b(acc[i][j][r]);
            }
    } else {
        u16* Ct = smem;   // [128][264]
        u16* Cb = C + (long)b * strideC;
#pragma unroll
        for (int h = 0; h < 2; h++) {
            __syncthreads();
            if ((wc >> 1) == h) {
#pragma unroll
                for (int i = 0; i < 8; i++)
#pragma unroll
                    for (int j = 0; j < 4; j++) {
                        int nn = (wc & 1) * 64 + j * 16 + r16;
                        int mm = wr * 128 + i * 16 + quad * 4;
                        ushort4 pk;
                        pk.x = f2b(acc[i][j][0]); pk.y = f2b(acc[i][j][1]);
                        pk.z = f2b(acc[i][j][2]); pk.w = f2b(acc[i][j][3]);
                        *(ushort4*)(Ct + nn * 264 + mm) = pk;
                    }
            }
            __syncthreads();
#pragma unroll
            for (int e = 0; e < 8; e++) {
                int idx = e * 512 + t;
                int n = idx >> 5, m8 = (idx & 31) * 8;
                uint4 v = *(const uint4*)(Ct + n * 264 + m8);
                *(uint4*)(Cb + (long)(n0 + h * 128 + n) * M + m0 + m8) = v;
            }
        }
    }
}
#undef PHASE_SYNC

// ------------------------------------------------------------- attention ---
// Phase 1: partial S over 1024-pixel chunks, 512 blocks, atomicAdd reduce.
__global__ __launch_bounds__(256) void attn_s(const u16* __restrict__ QKV, float* __restrict__ S)
{
    const int chunk = blockIdx.x, bhp = blockIdx.y;
    const int bi = bhp >> 5, h = (bhp >> 2) & 7, p = bhp & 3;
    const long rs = 16384;
    const u16* base = QKV + (long)bi * (3072L * 4096) + (long)(h * 384 + p) * 4096;
    const int t = threadIdx.x, l = t & 63, w = t >> 6;
    const int quad = l >> 4, r16 = l & 15;
    __shared__ float Sred[4][32][32];

    f32x4 acc[2][2];
#pragma unroll
    for (int i = 0; i < 2; i++)
#pragma unroll
        for (int j = 0; j < 2; j++) acc[i][j] = (f32x4){0.f, 0.f, 0.f, 0.f};

    const int nb = chunk * 1024 + w * 256 + quad * 8;
    for (int kk = 0; kk < 256; kk += 32) {
        long off = nb + kk;
        bf16x8 q0 = *(const bf16x8*)(base + (long)r16 * rs + off);
        bf16x8 q1 = *(const bf16x8*)(base + (long)(16 + r16) * rs + off);
        bf16x8 k0 = *(const bf16x8*)(base + (long)(32 + r16) * rs + off);
        bf16x8 k1 = *(const bf16x8*)(base + (long)(48 + r16) * rs + off);
        acc[0][0] = __builtin_amdgcn_mfma_f32_16x16x32_bf16(q0, k0, acc[0][0], 0, 0, 0);
        acc[0][1] = __builtin_amdgcn_mfma_f32_16x16x32_bf16(q0, k1, acc[0][1], 0, 0, 0);
        acc[1][0] = __builtin_amdgcn_mfma_f32_16x16x32_bf16(q1, k0, acc[1][0], 0, 0, 0);
        acc[1][1] = __builtin_amdgcn_mfma_f32_16x16x32_bf16(q1, k1, acc[1][1], 0, 0, 0);
    }
#pragma unroll
    for (int i = 0; i < 2; i++)
#pragma unroll
        for (int j = 0; j < 2; j++)
#pragma unroll
            for (int r = 0; r < 4; r++)
                Sred[w][i * 16 + quad * 4 + r][j * 16 + r16] = acc[i][j][r];
    __syncthreads();
    for (int e = t; e < 1024; e += 256) {
        int c = e >> 5, d = e & 31;
        float v = Sred[0][c][d] + Sred[1][c][d] + Sred[2][c][d] + Sred[3][c][d];
        atomicAdd(&S[(long)bhp * 1024 + e], v);
    }
}

// Phase 2: O = P V with fused scale+softmax on the LDS-resident S tile.
__global__ __launch_bounds__(256) void attn_pv(const u16* __restrict__ QKV, const float* __restrict__ S,
                                               u16* __restrict__ O)
{
    const int ns = blockIdx.x * 512, bhp = blockIdx.y;
    const int bi = bhp >> 5, h = (bhp >> 2) & 7, p = bhp & 3;
    const long rs = 16384;
    const u16* base = QKV + (long)bi * (3072L * 4096) + (long)(h * 384 + p) * 4096;
    const int t = threadIdx.x;
    __shared__ float Pl[1024];
    for (int e = t; e < 1024; e += 256) Pl[e] = S[(long)bhp * 1024 + e];
    __syncthreads();
    if (t < 32) {   // row-softmax of the 32x32 S tile
        float r[32];
        float mx = -1e30f;
#pragma unroll
        for (int d = 0; d < 32; d++) { r[d] = Pl[t * 32 + d] * 0.17677669529663687f; mx = fmaxf(mx, r[d]); }
        float sum = 0.f;
#pragma unroll
        for (int d = 0; d < 32; d++) { r[d] = __expf(r[d] - mx); sum += r[d]; }
        float inv = 1.f / sum;
#pragma unroll
        for (int d = 0; d < 32; d++) Pl[t * 32 + d] = r[d] * inv;
    }
    __syncthreads();

    float v[32][2];
#pragma unroll
    for (int d = 0; d < 32; d++) {
        unsigned int u = *(const unsigned int*)(base + (long)(64 + d) * rs + ns + 2 * t);
        v[d][0] = b2f((u16)u); v[d][1] = b2f((u16)(u >> 16));
    }
    u16* Ob = O + (long)bi * (1024L * 4096) + (long)(h * 128 + p) * 4096;
    for (int c = 0; c < 32; c++) {
        float s0 = 0.f, s1 = 0.f;
        const float4* prow = (const float4*)(&Pl[c * 32]);
#pragma unroll
        for (int dq = 0; dq < 8; dq++) {
            float4 pv = prow[dq];
            s0 = fmaf(pv.x, v[4*dq+0][0], s0); s1 = fmaf(pv.x, v[4*dq+0][1], s1);
            s0 = fmaf(pv.y, v[4*dq+1][0], s0); s1 = fmaf(pv.y, v[4*dq+1][1], s1);
            s0 = fmaf(pv.z, v[4*dq+2][0], s0); s1 = fmaf(pv.z, v[4*dq+2][1], s1);
            s0 = fmaf(pv.w, v[4*dq+3][0], s0); s1 = fmaf(pv.w, v[4*dq+3][1], s1);
        }
        *(unsigned int*)(Ob + (long)c * 16384 + ns + 2 * t) =
            (unsigned int)f2b(s0) | ((unsigned int)f2b(s1) << 16);
    }
}

// ------------------------------------------------------ pe conv + residual ---
// MFMA version.  Per block: (16x16 px tile, group g, batch bi).  The 3x3
// group-conv is OUT[of][px] = RES + sum_k W[of][k] IN[k][px], k = tap*16+fi
// (144 real k, padded to 160 = 5 MFMA K-steps of 32 = 2 taps x 16 fi).
//   A-frag: Wpe16 prebuilt in fragment order (lane(quad,r16): W[of=r16][k]).
//   B-frag: halo tile in LDS as [spatial][fi] (row pad 24 u16) -- lane
//           (quad,r16) reads 16B at tin2[sp(px=r16, tap)][fi0]: exactly
//           B[k][col=px].  tap = kt*2+(quad>>1), fi0 = (quad&1)*8.
//   C/D: col=px=r16 (x), row=of=quad*4+reg; residual preloaded into C-in;
//        ushort4 store is feature-contiguous in O2t.
__global__ __launch_bounds__(256) void pe_kernel(const u16* __restrict__ Oin,
                                                 const u16* __restrict__ Wpe,
                                                 u16* __restrict__ O2t)
{
    const int tile = blockIdx.x, g = blockIdx.y, bi = blockIdx.z;
    const int y0 = (tile >> 2) * 16, x0 = (tile & 3) * 16;
    __shared__ u16 tin2[324][24];   // [18x18 spatial][fi], pad 16->24 for banks
    const int t = threadIdx.x;
    const u16* Ob = Oin + (long)bi * (1024L * 4096) + (long)(g * 16) * 4096;
    for (int e = t; e < 4 * 324; e += 256) {   // 4 fi per thread, ushort4 write
        int f0 = (e / 324) * 4, rem = e % 324;
        int yy = rem / 18 - 1 + y0, xx = rem % 18 - 1 + x0;
        ushort4 v = {0, 0, 0, 0};
        if (yy >= 0 && yy < 64 && xx >= 0 && xx < 64) {
            long o = (long)yy * 64 + xx;
            v.x = Ob[(long)(f0 + 0) * 4096 + o];
            v.y = Ob[(long)(f0 + 1) * 4096 + o];
            v.z = Ob[(long)(f0 + 2) * 4096 + o];
            v.w = Ob[(long)(f0 + 3) * 4096 + o];
        }
        *(ushort4*)(&tin2[rem][f0]) = v;
    }
    __syncthreads();

    const int l = t & 63, w = t >> 6;
    const int quad = l >> 4, r16 = l & 15;     // r16 = x = D-col; of rows = quad*4+reg
    const u16* Wg = Wpe + g * 2560;
    bf16x8 af[5];
#pragma unroll
    for (int kt = 0; kt < 5; kt++)
        af[kt] = *(const bf16x8*)(Wg + kt * 512 + quad * 128 + r16 * 8);

    const int tap_base = quad >> 1, fi0 = (quad & 1) * 8;
#pragma unroll
    for (int i = 0; i < 4; i++) {
        int y = w * 4 + i;
        // residual -> C-in (lane holds rows of=quad*4+0..3 at px=(y,x=r16))
        const u16* rc = &tin2[(y + 1) * 18 + (r16 + 1)][quad * 4];
        f32x4 acc;
        acc[0] = b2f(rc[0]); acc[1] = b2f(rc[1]); acc[2] = b2f(rc[2]); acc[3] = b2f(rc[3]);
#pragma unroll
        for (int kt = 0; kt < 5; kt++) {
            int tap = kt * 2 + tap_base;        // 0..9; tap 9 has zero weights
            int sp = (tap < 9) ? (y + tap / 3) * 18 + (r16 + tap % 3) : 0;
            bf16x8 bf = *(const bf16x8*)(&tin2[sp][fi0]);
            acc = __builtin_amdgcn_mfma_f32_16x16x32_bf16(af[kt], bf, acc, 0, 0, 0);
        }
        long n = (long)(y0 + y) * 64 + (x0 + r16);
        ushort4 pk;
        pk.x = f2b(acc[0]); pk.y = f2b(acc[1]); pk.z = f2b(acc[2]); pk.w = f2b(acc[3]);
        *(ushort4*)(O2t + ((long)bi * 4096 + n) * 1024 + g * 16 + quad * 4) = pk;
    }
}

// ----------------------------------------- BN stats, feature-major layout ---
__global__ __launch_bounds__(256) void bn_stats(const u16* __restrict__ X, float* __restrict__ stats, int M)
{
    const int m = blockIdx.x, t = threadIdx.x;
    float s = 0.f, ss = 0.f;
    for (int b = 0; b < 4; b++) {
        const u16* rowp = X + ((long)b * M + m) * 4096;
        for (int pass = 0; pass < 2; pass++) {
            uint4 uv = *(const uint4*)(rowp + pass * 2048 + t * 8);
            unsigned int wsa[4] = {uv.x, uv.y, uv.z, uv.w};
#pragma unroll
            for (int u = 0; u < 4; u++) {
                float v0 = b2f((u16)wsa[u]), v1 = b2f((u16)(wsa[u] >> 16));
                s += v0 + v1; ss += v0 * v0 + v1 * v1;
            }
        }
    }
    __shared__ float rs[4], rss[4];
    for (int o = 32; o > 0; o >>= 1) { s += __shfl_down(s, o); ss += __shfl_down(ss, o); }
    if ((t & 63) == 0) { rs[t >> 6] = s; rss[t >> 6] = ss; }
    __syncthreads();
    if (t == 0) {
        float S = rs[0] + rs[1] + rs[2] + rs[3];
        float SS = rss[0] + rss[1] + rss[2] + rss[3];
        float mean = S * (1.f / 16384.f);
        float var = SS * (1.f / 16384.f) - mean * mean;
        stats[2 * m] = mean;
        stats[2 * m + 1] = rsqrtf(var + 1e-5f);
    }
}

// ------------------------------------------- X1t = cast_tr(x + BN(P)) bf16 ---
__global__ __launch_bounds__(256) void bn_add_tr(const float* __restrict__ x, const u16* __restrict__ P,
    const float* __restrict__ stats, const float* __restrict__ gamma, const float* __restrict__ beta,
    u16* __restrict__ X1t)
{
    int b = blockIdx.z, mt = blockIdx.y * 64, nt = blockIdx.x * 64;
    __shared__ u16 tl[64][66];
    int t = threadIdx.x, sub = t >> 4, c4 = (t & 15) * 4;
#pragma unroll
    for (int rr = 0; rr < 4; rr++) {
        int row = rr * 16 + sub, m = mt + row;
        float gm = gamma[m] * stats[2 * m + 1];
        float bs = beta[m] - gm * stats[2 * m];
        long gi = ((long)b * 1024 + m) * 4096 + nt + c4;
        float4 xv = *(const float4*)(x + gi);
        uint2 pv = *(const uint2*)(P + gi);
        uint2 pk;
        pk.x = (unsigned int)f2b(xv.x + fmaf(gm, b2f((u16)pv.x), bs)) |
               ((unsigned int)f2b(xv.y + fmaf(gm, b2f((u16)(pv.x >> 16)), bs)) << 16);
        pk.y = (unsigned int)f2b(xv.z + fmaf(gm, b2f((u16)pv.y), bs)) |
               ((unsigned int)f2b(xv.w + fmaf(gm, b2f((u16)(pv.y >> 16)), bs)) << 16);
        *(uint2*)(&tl[row][c4]) = pk;
    }
    __syncthreads();
#pragma unroll
    for (int rr = 0; rr < 4; rr++) {
        int row = rr * 16 + sub;
        uint2 o;
        o.x = (unsigned int)tl[c4][row] | ((unsigned int)tl[c4 + 1][row] << 16);
        o.y = (unsigned int)tl[c4 + 2][row] | ((unsigned int)tl[c4 + 3][row] << 16);
        *(uint2*)(X1t + ((long)b * 4096 + nt + row) * 1024 + mt + c4) = o;
    }
}

// ----------------------------- BN stats over pixel-major [16384][2048] bf16 ---
__global__ __launch_bounds__(256) void bn_stats_col(const u16* __restrict__ Xp, float* __restrict__ accum)
{
    const int t = threadIdx.x;
    const int f0 = t * 8;
    float s[8], ss[8];
#pragma unroll
    for (int u = 0; u < 8; u++) { s[u] = 0.f; ss[u] = 0.f; }
    const u16* base = Xp + (long)blockIdx.x * 128 * 2048;
    for (int r = 0; r < 128; r++) {
        uint4 uv = *(const uint4*)(base + (long)r * 2048 + f0);
        unsigned int wsa[4] = {uv.x, uv.y, uv.z, uv.w};
#pragma unroll
        for (int u = 0; u < 4; u++) {
            float v0 = b2f((u16)wsa[u]), v1 = b2f((u16)(wsa[u] >> 16));
            s[2*u] += v0;   ss[2*u]   += v0 * v0;
            s[2*u+1] += v1; ss[2*u+1] += v1 * v1;
        }
    }
#pragma unroll
    for (int u = 0; u < 8; u++) {
        atomicAdd(&accum[f0 + u], s[u]);
        atomicAdd(&accum[2048 + f0 + u], ss[u]);
    }
}

// --------------------------------- in-place relu(BN(.)) on pixel-major F1 ---
__global__ __launch_bounds__(256) void bn_relu_ip(u16* __restrict__ Xp, const float* __restrict__ accum,
    const float* __restrict__ gamma, const float* __restrict__ beta)
{
    long i = ((long)blockIdx.x * 256 + threadIdx.x) * 8;
    int f = (int)(i & 2047);
    uint4 uv = *(const uint4*)(Xp + i);
    unsigned int wsa[4] = {uv.x, uv.y, uv.z, uv.w};
    unsigned int ov[4];
#pragma unroll
    for (int u = 0; u < 4; u++) {
        unsigned int o = 0;
#pragma unroll
        for (int h = 0; h < 2; h++) {
            int ff = f + 2 * u + h;
            float S = accum[ff], SS = accum[2048 + ff];
            float mean = S * (1.f / 16384.f);
            float var = SS * (1.f / 16384.f) - mean * mean;
            float g = gamma[ff] * rsqrtf(var + 1e-5f);
            float bb = beta[ff] - g * mean;
            float xv = b2f((u16)(wsa[u] >> (16 * h)));
            float v = fmaxf(fmaf(g, xv, bb), 0.f);
            o |= ((unsigned int)f2b(v)) << (16 * h);
        }
        ov[u] = o;
    }
    *(uint4*)(Xp + i) = *(uint4*)ov;
}

// ---------------------- out[b][m][n] fp32 = X1t[b][n][m] + BN3(F2[b][m][n]) ---
__global__ __launch_bounds__(256) void final_tr(const u16* __restrict__ X1t, const u16* __restrict__ F2,
    const float* __restrict__ stats, const float* __restrict__ gamma, const float* __restrict__ beta,
    float* __restrict__ out)
{
    int b = blockIdx.z, mt = blockIdx.y * 64, nt = blockIdx.x * 64;
    __shared__ u16 tl[64][66];
    int t = threadIdx.x, sub = t >> 4, c4 = (t & 15) * 4;
#pragma unroll
    for (int rr = 0; rr < 4; rr++) {
        int row = rr * 16 + sub;  // pixel index within tile
        uint2 v = *(const uint2*)(X1t + ((long)b * 4096 + nt + row) * 1024 + mt + c4);
        *(uint2*)(&tl[row][c4]) = v;
    }
    __syncthreads();
#pragma unroll
    for (int rr = 0; rr < 4; rr++) {
        int row = rr * 16 + sub, m = mt + row;
        float gm = gamma[m] * stats[2 * m + 1];
        float bs = beta[m] - gm * stats[2 * m];
        long gi = ((long)b * 1024 + m) * 4096 + nt + c4;
        uint2 f = *(const uint2*)(F2 + gi);
        float4 o;
        o.x = b2f(tl[c4][row])     + fmaf(gm, b2f((u16)f.x), bs);
        o.y = b2f(tl[c4 + 1][row]) + fmaf(gm, b2f((u16)(f.x >> 16)), bs);
        o.z = b2f(tl[c4 + 2][row]) + fmaf(gm, b2f((u16)f.y), bs);
        o.w = b2f(tl[c4 + 3][row]) + fmaf(gm, b2f((u16)(f.y >> 16)), bs);
        *(float4*)(out + gi) = o;
    }
}

extern "C" void kernel_launch(void* const* d_in, const int* in_sizes, int n_in,
                              void* d_out, int out_size, void* d_ws, size_t ws_size,
                              hipStream_t stream)
{
    const float* x     = (const float*)d_in[0];
    const float* wqkv  = (const float*)d_in[1];
    const float* wproj = (const float*)d_in[2];
    const float* wpe   = (const float*)d_in[3];
    const float* g_n   = (const float*)d_in[4];
    const float* b_n   = (const float*)d_in[5];
    const float* wf1   = (const float*)d_in[6];
    const float* g_f1  = (const float*)d_in[7];
    const float* b_f1  = (const float*)d_in[8];
    const float* wf2   = (const float*)d_in[9];
    const float* g_f2  = (const float*)d_in[10];
    const float* b_f2  = (const float*)d_in[11];
    float* out = (float*)d_out;
    char* ws = (char*)d_ws;

    // workspace layout (~145.1 MiB):
    //   [0, 17.4M)        weights (persistent; Wpe16 = 328 KB u16 frags)
    //   [17.4M, 17.9M)    st1 | accum2+Sbuf (zeroed in prologue) | st3
    //   [17.9M, 118.6M)   QKV -> {O2t,X1t}@17.9M + {P,F1p}@51.5M
    //   [118.6M, 152.1M)  Xt -> Oat -> F2
    u16*   Wq      = (u16*)(ws + 0);
    u16*   Wp      = (u16*)(ws + 6291456);
    u16*   W1      = (u16*)(ws + 8388608);
    u16*   W2      = (u16*)(ws + 12582912);
    u16*   Wpe16   = (u16*)(ws + 16777216);
    float* st1     = (float*)(ws + 17367040);
    float* accum2  = (float*)(ws + 17375232);   // 4096 floats, then Sbuf 131072 floats
    float* Sbuf    = (float*)(ws + 17391616);   // 128 x 1024 fp32
    float* st3     = (float*)(ws + 17915904);
    u16*   QKV = (u16*)(ws + 17924096);         // 100.7 MB
    u16*   O2t = (u16*)(ws + 17924096);         // 33.5 MB
    u16*   X1t = (u16*)(ws + 17924096);         // 33.5 MB
    u16*   P   = (u16*)(ws + 51478528);         // 33.5 MB
    u16*   F1p = (u16*)(ws + 51478528);         // 67 MB (pixel-major)
    u16*   Xt  = (u16*)(ws + 118587392);        // 33.5 MB
    u16*   Oat = (u16*)(ws + 118587392);        // 33.5 MB
    u16*   F2  = (u16*)(ws + 118587392);        // 33.5 MB

    prologue<<<38032, 256, 0, stream>>>(x, wqkv, wproj, wf1, wf2, wpe,
                                        accum2, Wq, Wp, W1, W2, Wpe16, Xt);
    gemm256<false><<<dim3(16, 12, 4), 512, 0, stream>>>(Wq, Xt, QKV, 3072, 4096, 1024, 4096L * 1024, 3072L * 4096);
    attn_s<<<dim3(4, 128), 256, 0, stream>>>(QKV, Sbuf);
    attn_pv<<<dim3(8, 128), 256, 0, stream>>>(QKV, Sbuf, Oat);
    pe_kernel<<<dim3(16, 64, 4), 256, 0, stream>>>(Oat, Wpe16, O2t);
    gemm256<false><<<dim3(16, 4, 4), 512, 0, stream>>>(Wp, O2t, P, 1024, 4096, 1024, 4096L * 1024, 1024L * 4096);
    bn_stats<<<1024, 256, 0, stream>>>(P, st1, 1024);
    bn_add_tr<<<dim3(64, 16, 4), 256, 0, stream>>>(x, P, st1, g_n, b_n, X1t);
    gemm256<true><<<dim3(16, 8, 4), 512, 0, stream>>>(W1, X1t, F1p, 2048, 4096, 1024, 4096L * 1024, 4096L * 2048);
    bn_stats_col<<<128, 256, 0, stream>>>(F1p, accum2);
    bn_relu_ip<<<16384, 256, 0, stream>>>(F1p, accum2, g_f1, b_f1);
    gemm256<false><<<dim3(16, 4, 4), 512, 0, stream>>>(W2, F1p, F2, 1024, 4096, 2048, 4096L * 2048, 1024L * 4096);
    bn_stats<<<1024, 256, 0, stream>>>(F2, st3, 1024);
    final_tr<<<dim3(64, 16, 4), 256, 0, stream>>>(X1t, F2, st3, g_f2, b_f2, out);
}